// Round 6
// baseline (277.083 us; speedup 1.0000x reference)
//
#include <hip/hip_runtime.h>
#include <hip/hip_bf16.h>
#include <hip/hip_fp16.h>
#include <cstdint>

// ProbSparse attention (Informer). B=4, L=2048, H=8, D=64, sample_k=u=40.
#define BB 4
#define LL 2048
#define HH 8
#define DD 64
#define SK 40
#define UU 40
#define LDK 68     // LDS row pitch (floats): 68 ≡ 4 mod 32 banks
#define NSEG32 64  // 64 segments of 32 keys (primary path)
#define NSEG64 32  // 32 segments of 64 keys (fallback path)
#define PSTRIDE 34 // Part entry: [f32 m][f32 l][64 x half] = 136 B = 34 floats

// ---------------------------------------------------------------------------
// Kernel 1: M[b,h,q] = max_s(Q·K_s) - mean_s(Q·K_s).  Wave per query, lane
// per sample: 16 independent float4 gathers per lane (deep MLP), Q row via
// LDS broadcast. Grid 16384 (16 blocks/CU over time); 4 bh per XCD.
// ---------------------------------------------------------------------------
__global__ __launch_bounds__(256) void k_sample_score(
    const float* __restrict__ Q, const float* __restrict__ K,
    const int* __restrict__ idxs, float* __restrict__ M) {
  int j = blockIdx.x;                 // 0..16383
  int xcd = j & 7, r = j >> 3;        // r 0..2047
  int bh = (xcd << 2) | (r >> 9);     // 4 bh per XCD
  int qg = r & 511;                   // 512 query-groups of 4
  int b = bh >> 3, h = bh & 7;
  int t = threadIdx.x, w = t >> 6, lane = t & 63;
  int q = qg * 4 + w;

  __shared__ float qs[4][64];
  qs[w][lane] = Q[((size_t)((b * LL + q) * HH + h)) * DD + lane];

  int sd = (lane < SK) ? idxs[q * SK + lane] : 0;
  __syncthreads();

  const float4* kv = reinterpret_cast<const float4*>(
      K + ((size_t)((b * LL + sd) * HH + h)) * DD);
  const float4* qv = reinterpret_cast<const float4*>(qs[w]);
  float4 a = {0.f, 0.f, 0.f, 0.f};
#pragma unroll
  for (int jj = 0; jj < 16; jj++) {
    float4 c = kv[jj];
    float4 qq = qv[jj];              // LDS broadcast (same addr per wave)
    a.x += c.x * qq.x; a.y += c.y * qq.y;
    a.z += c.z * qq.z; a.w += c.w * qq.w;
  }
  float dot = (a.x + a.y) + (a.z + a.w);
  float mx = (lane < SK) ? dot : -1e30f;
  float sm = (lane < SK) ? dot : 0.f;
#pragma unroll
  for (int s = 1; s < 64; s <<= 1) {
    mx = fmaxf(mx, __shfl_xor(mx, s));
    sm += __shfl_xor(sm, s);
  }
  if (lane == 0) M[bh * LL + q] = mx - sm * (1.0f / SK);
}

// ---------------------------------------------------------------------------
// Kernel 2: top-40 of M[b,h,:]. One wave; 32 packed u64 keys/lane in regs.
// key = (ordered_float<<32)|~idx -> max == (max val, lowest idx).
// ---------------------------------------------------------------------------
__global__ __launch_bounds__(64) void k_topk(const float* __restrict__ M,
                                             int* __restrict__ Mtop) {
  int bh = blockIdx.x;
  int lane = threadIdx.x;
  unsigned long long key[32];
  unsigned long long lmax = 0ull;
#pragma unroll
  for (int i = 0; i < 32; i++) {
    int e = i * 64 + lane;
    unsigned u = __float_as_uint(M[bh * LL + e]);
    u = (u & 0x80000000u) ? ~u : (u | 0x80000000u);
    key[i] = ((unsigned long long)u << 32) | (unsigned)(~e);
    lmax = key[i] > lmax ? key[i] : lmax;
  }
  for (int it = 0; it < UU; it++) {
    unsigned long long best = lmax;
#pragma unroll
    for (int s = 1; s < 64; s <<= 1) {
      unsigned long long o = __shfl_xor(best, s);
      best = o > best ? o : best;
    }
    int e = (int)(~(unsigned)best) & (LL - 1);
    if (lane == 0) Mtop[bh * UU + it] = e;
    if ((e & 63) == lane) {
      int slot = e >> 6;
#pragma unroll
      for (int i = 0; i < 32; i++)
        if (i == slot) key[i] = 0ull;
      lmax = 0ull;
#pragma unroll
      for (int i = 0; i < 32; i++) lmax = key[i] > lmax ? key[i] : lmax;
    }
  }
}

// ---------------------------------------------------------------------------
// Cumsum stage A: 16-row chunk sums, vectorized. 64 thr: lane=(d4 0..15,
// r4 0..3); each lane sums 4 rows x float4; cross-r4 reduce via shfl.
// ---------------------------------------------------------------------------
__global__ __launch_bounds__(64) void k_chunksum16(const float* __restrict__ V,
                                                   float* __restrict__ CS16) {
  int j = blockIdx.x;                 // 0..4095
  int xcd = j & 7, r = j >> 3;        // r 0..511
  int bh = (xcd << 2) | (r >> 7);
  int c = r & 127;
  int b = bh >> 3, h = bh & 7;
  int t = threadIdx.x, d4 = t & 15, r4 = t >> 4;
  const float4* vp = reinterpret_cast<const float4*>(
      V + ((size_t)((b * LL + c * 16 + r4 * 4) * HH + h)) * DD) + d4;
  float4 v0 = vp[0], v1 = vp[128], v2 = vp[256], v3 = vp[384];
  float4 s;
  s.x = v0.x + v1.x + v2.x + v3.x;
  s.y = v0.y + v1.y + v2.y + v3.y;
  s.z = v0.z + v1.z + v2.z + v3.z;
  s.w = v0.w + v1.w + v2.w + v3.w;
#pragma unroll
  for (int sh = 16; sh < 64; sh <<= 1) {
    s.x += __shfl_xor(s.x, sh);
    s.y += __shfl_xor(s.y, sh);
    s.z += __shfl_xor(s.z, sh);
    s.w += __shfl_xor(s.w, sh);
  }
  if (r4 == 0)
    *reinterpret_cast<float4*>(CS16 + ((size_t)bh * 128 + c) * 64 + d4 * 4) = s;
}

// ---------------------------------------------------------------------------
// Cumsum stage B: exclusive prefix over 128 chunk-sums per bh.
// Block per bh, 256 thr: wave w owns chunks w*32..w*32+31 for all 64 d.
// ---------------------------------------------------------------------------
__global__ __launch_bounds__(256) void k_prefix16(const float* __restrict__ CS16,
                                                  float* __restrict__ PS16) {
  int bh = blockIdx.x;
  int t = threadIdx.x, w = t >> 6, d = t & 63;
  float cs[32];
  const float* base = CS16 + ((size_t)bh * 128 + w * 32) * 64 + d;
#pragma unroll
  for (int cc = 0; cc < 32; cc++) cs[cc] = base[cc * 64];
  float tot = 0.f;
#pragma unroll
  for (int cc = 0; cc < 32; cc++) tot += cs[cc];
  __shared__ float totw[4][64];
  totw[w][d] = tot;
  __syncthreads();
  float run = 0.f;
#pragma unroll
  for (int w2 = 0; w2 < 4; w2++)
    if (w2 < w) run += totw[w2][d];
  float* pbase = PS16 + ((size_t)bh * 128 + w * 32) * 64 + d;
#pragma unroll
  for (int cc = 0; cc < 32; cc++) { pbase[cc * 64] = run; run += cs[cc]; }
}

// ---------------------------------------------------------------------------
// Cumsum stage C: write Out rows. In-register 4-row prefix + shfl_up scan
// across the 4 row-groups. Fully float4 vectorized (1 KB/instr).
// ---------------------------------------------------------------------------
__global__ __launch_bounds__(64) void k_cumsum16(const float* __restrict__ V,
                                                 const float* __restrict__ PS16,
                                                 float* __restrict__ Out) {
  int j = blockIdx.x;
  int xcd = j & 7, r = j >> 3;
  int bh = (xcd << 2) | (r >> 7);
  int c = r & 127;
  int b = bh >> 3, h = bh & 7;
  int t = threadIdx.x, d4 = t & 15, r4 = t >> 4;
  size_t rowbase = ((size_t)((b * LL + c * 16 + r4 * 4) * HH + h)) * DD;
  const float4* vp = reinterpret_cast<const float4*>(V + rowbase) + d4;
  float4 v0 = vp[0], v1 = vp[128], v2 = vp[256], v3 = vp[384];
  float4 i0 = v0;
  float4 i1 = {i0.x + v1.x, i0.y + v1.y, i0.z + v1.z, i0.w + v1.w};
  float4 i2 = {i1.x + v2.x, i1.y + v2.y, i1.z + v2.z, i1.w + v2.w};
  float4 i3 = {i2.x + v3.x, i2.y + v3.y, i2.z + v3.z, i2.w + v3.w};
  // inclusive scan of group-totals (i3) across r4 (stride-16 lanes)
  float4 incl = i3;
  float4 u1;
  u1.x = __shfl_up(incl.x, 16); u1.y = __shfl_up(incl.y, 16);
  u1.z = __shfl_up(incl.z, 16); u1.w = __shfl_up(incl.w, 16);
  if (r4 >= 1) { incl.x += u1.x; incl.y += u1.y; incl.z += u1.z; incl.w += u1.w; }
  float4 u2;
  u2.x = __shfl_up(incl.x, 32); u2.y = __shfl_up(incl.y, 32);
  u2.z = __shfl_up(incl.z, 32); u2.w = __shfl_up(incl.w, 32);
  if (r4 >= 2) { incl.x += u2.x; incl.y += u2.y; incl.z += u2.z; incl.w += u2.w; }
  float4 ex = {incl.x - i3.x, incl.y - i3.y, incl.z - i3.z, incl.w - i3.w};
  float4 ps = *reinterpret_cast<const float4*>(
      PS16 + ((size_t)bh * 128 + c) * 64 + d4 * 4);
  float4 base4 = {ps.x + ex.x, ps.y + ex.y, ps.z + ex.z, ps.w + ex.w};
  float4* op = reinterpret_cast<float4*>(Out + rowbase) + d4;
  float4 o;
  o = {base4.x + i0.x, base4.y + i0.y, base4.z + i0.z, base4.w + i0.w}; op[0]   = o;
  o = {base4.x + i1.x, base4.y + i1.y, base4.z + i1.z, base4.w + i1.w}; op[128] = o;
  o = {base4.x + i2.x, base4.y + i2.y, base4.z + i2.z, base4.w + i2.w}; op[256] = o;
  o = {base4.x + i3.x, base4.y + i3.y, base4.z + i3.z, base4.w + i3.w}; op[384] = o;
}

// ---------------------------------------------------------------------------
// Kernel 4a (primary): partial attention, 32-key segments. Block = (bh,seg).
// 17.6 KB LDS -> 8 blocks/CU; fine-grained causal-triangle balance.
// Partial (m,l,acc[64]) -> Part (acc in fp16).
// ---------------------------------------------------------------------------
__global__ __launch_bounds__(256) void k_attn_part32(
    const float* __restrict__ Q, const float* __restrict__ K,
    const float* __restrict__ V, const int* __restrict__ Mtop,
    float* __restrict__ Part) {
  int j = blockIdx.x;                  // 0..2047
  int xcd = j & 7, r_ = j >> 3;        // 0..255
  int bh = (xcd << 2) | (r_ & 3);
  int seg = r_ >> 2;                   // 0..63
  int b = bh >> 3, h = bh & 7;
  int s0 = seg * 32;

  int t = threadIdx.x;
  int w = t >> 6, lane = t & 63;
  int kk = lane & 15, gg = lane >> 4;

  __shared__ float Kt[32 * LDK];
  __shared__ float Vt[32 * LDK];
  __shared__ int midx[UU];

  if (t < UU) midx[t] = Mtop[bh * UU + t];

  const float4* kg = reinterpret_cast<const float4*>(
      K + ((size_t)((b * LL + s0) * HH + h)) * DD);
  const float4* vg = reinterpret_cast<const float4*>(
      V + ((size_t)((b * LL + s0) * HH + h)) * DD);
#pragma unroll
  for (int i = 0; i < 2; i++) {
    int f = t + i * 256;               // 0..511 float4 slots
    int r = f >> 4, col = f & 15;
    float4 kv4 = kg[(size_t)r * (HH * DD / 4) + col];
    float4 vv4 = vg[(size_t)r * (HH * DD / 4) + col];
    *reinterpret_cast<float4*>(&Kt[r * LDK + col * 4]) = kv4;
    *reinterpret_cast<float4*>(&Vt[r * LDK + col * 4]) = vv4;
  }
  __syncthreads();

  for (int uu = 0; uu < 10; uu++) {
    int u = w + uu * 4;
    int idx = midx[u];
    if (idx < s0) continue;            // wave-uniform skip
    int kend = idx - s0;
    if (kend > 31) kend = 31;

    const float4* qv = reinterpret_cast<const float4*>(
        Q + ((size_t)((b * LL + idx) * HH + h)) * DD + gg * 16);
    float4 qr0 = qv[0], qr1 = qv[1], qr2 = qv[2], qr3 = qv[3];

    float m = -1e30f, l = 0.f, acc = 0.f;
#pragma unroll
    for (int ks = 0; ks < 2; ks++) {
      if (ks * 16 > kend) break;       // uniform
      int row = ks * 16 + kk;
      float dp = 0.f;
      const float4* kr = reinterpret_cast<const float4*>(&Kt[row * LDK + gg * 16]);
      float4 c0 = kr[0], c1 = kr[1], c2 = kr[2], c3 = kr[3];
      dp += qr0.x * c0.x + qr0.y * c0.y + qr0.z * c0.z + qr0.w * c0.w;
      dp += qr1.x * c1.x + qr1.y * c1.y + qr1.z * c1.z + qr1.w * c1.w;
      dp += qr2.x * c2.x + qr2.y * c2.y + qr2.z * c2.z + qr2.w * c2.w;
      dp += qr3.x * c3.x + qr3.y * c3.y + qr3.z * c3.z + qr3.w * c3.w;
      dp += __shfl_xor(dp, 16);
      dp += __shfl_xor(dp, 32);
      bool valid = (row <= kend);
      float s = valid ? dp * 0.125f : -1e30f;
      float cm = s;
      cm = fmaxf(cm, __shfl_xor(cm, 1));
      cm = fmaxf(cm, __shfl_xor(cm, 2));
      cm = fmaxf(cm, __shfl_xor(cm, 4));
      cm = fmaxf(cm, __shfl_xor(cm, 8));
      float mn = fmaxf(m, cm);
      float f_ = __expf(m - mn);
      float p = valid ? __expf(s - mn) : 0.f;
      float ps = p;
      ps += __shfl_xor(ps, 1);
      ps += __shfl_xor(ps, 2);
      ps += __shfl_xor(ps, 4);
      ps += __shfl_xor(ps, 8);
      l = l * f_ + ps;
      m = mn;
      acc *= f_;
#pragma unroll
      for (int k2 = 0; k2 < 16; k2++) {
        float pk = __shfl(p, k2);
        acc += pk * Vt[(ks * 16 + k2) * LDK + lane];
      }
    }

    float* pb = Part + ((size_t)(bh * UU + u) * NSEG32 + seg) * PSTRIDE;
    __half* ph = reinterpret_cast<__half*>(pb + 2);
    ph[lane] = __float2half(acc);
    if (lane == 0) { pb[0] = m; pb[1] = l; }
  }
}

// ---------------------------------------------------------------------------
// Kernel 4a (fallback): 64-key segments, same Part layout (stride NSEG64).
// ---------------------------------------------------------------------------
__global__ __launch_bounds__(256) void k_attn_part64(
    const float* __restrict__ Q, const float* __restrict__ K,
    const float* __restrict__ V, const int* __restrict__ Mtop,
    float* __restrict__ Part) {
  int j = blockIdx.x;                  // 0..1023
  int xcd = j & 7, r_ = j >> 3;
  int bh = (xcd << 2) | (r_ & 3);
  int seg = r_ >> 2;                   // 0..31
  int b = bh >> 3, h = bh & 7;
  int s0 = seg * 64;

  int t = threadIdx.x;
  int w = t >> 6, lane = t & 63;
  int kk = lane & 15, gg = lane >> 4;

  __shared__ float Kt[64 * LDK];
  __shared__ float Vt[64 * LDK];
  __shared__ int midx[UU];

  if (t < UU) midx[t] = Mtop[bh * UU + t];

  const float4* kg = reinterpret_cast<const float4*>(
      K + ((size_t)((b * LL + s0) * HH + h)) * DD);
  const float4* vg = reinterpret_cast<const float4*>(
      V + ((size_t)((b * LL + s0) * HH + h)) * DD);
#pragma unroll
  for (int i = 0; i < 4; i++) {
    int f = t + i * 256;
    int r = f >> 4, col = f & 15;
    float4 kv4 = kg[(size_t)r * (HH * DD / 4) + col];
    float4 vv4 = vg[(size_t)r * (HH * DD / 4) + col];
    *reinterpret_cast<float4*>(&Kt[r * LDK + col * 4]) = kv4;
    *reinterpret_cast<float4*>(&Vt[r * LDK + col * 4]) = vv4;
  }
  __syncthreads();

  for (int uu = 0; uu < 10; uu++) {
    int u = w + uu * 4;
    int idx = midx[u];
    if (idx < s0) continue;
    int kend = idx - s0;
    if (kend > 63) kend = 63;

    const float4* qv = reinterpret_cast<const float4*>(
        Q + ((size_t)((b * LL + idx) * HH + h)) * DD + gg * 16);
    float4 qr0 = qv[0], qr1 = qv[1], qr2 = qv[2], qr3 = qv[3];

    float m = -1e30f, l = 0.f, acc = 0.f;
#pragma unroll
    for (int ks = 0; ks < 4; ks++) {
      if (ks * 16 > kend) break;
      int row = ks * 16 + kk;
      float dp = 0.f;
      const float4* kr = reinterpret_cast<const float4*>(&Kt[row * LDK + gg * 16]);
      float4 c0 = kr[0], c1 = kr[1], c2 = kr[2], c3 = kr[3];
      dp += qr0.x * c0.x + qr0.y * c0.y + qr0.z * c0.z + qr0.w * c0.w;
      dp += qr1.x * c1.x + qr1.y * c1.y + qr1.z * c1.z + qr1.w * c1.w;
      dp += qr2.x * c2.x + qr2.y * c2.y + qr2.z * c2.z + qr2.w * c2.w;
      dp += qr3.x * c3.x + qr3.y * c3.y + qr3.z * c3.z + qr3.w * c3.w;
      dp += __shfl_xor(dp, 16);
      dp += __shfl_xor(dp, 32);
      bool valid = (row <= kend);
      float s = valid ? dp * 0.125f : -1e30f;
      float cm = s;
      cm = fmaxf(cm, __shfl_xor(cm, 1));
      cm = fmaxf(cm, __shfl_xor(cm, 2));
      cm = fmaxf(cm, __shfl_xor(cm, 4));
      cm = fmaxf(cm, __shfl_xor(cm, 8));
      float mn = fmaxf(m, cm);
      float f_ = __expf(m - mn);
      float p = valid ? __expf(s - mn) : 0.f;
      float ps = p;
      ps += __shfl_xor(ps, 1);
      ps += __shfl_xor(ps, 2);
      ps += __shfl_xor(ps, 4);
      ps += __shfl_xor(ps, 8);
      l = l * f_ + ps;
      m = mn;
      acc *= f_;
#pragma unroll
      for (int k2 = 0; k2 < 16; k2++) {
        float pk = __shfl(p, k2);
        acc += pk * Vt[(ks * 16 + k2) * LDK + lane];
      }
    }

    float* pb = Part + ((size_t)(bh * UU + u) * NSEG64 + seg) * PSTRIDE;
    __half* ph = reinterpret_cast<__half*>(pb + 2);
    ph[lane] = __float2half(acc);
    if (lane == 0) { pb[0] = m; pb[1] = l; }
  }
}

// ---------------------------------------------------------------------------
// Kernel 4b: merge segment partials per (bh,u). Lane-per-segment weights,
// then weighted sum over fp16 accs. shift = log2(seg), nsegmax = stride.
// ---------------------------------------------------------------------------
__global__ __launch_bounds__(64) void k_attn_merge(
    const int* __restrict__ Mtop, const float* __restrict__ Part,
    float* __restrict__ Out, int shift, int nsegmax) {
  int blk = blockIdx.x;                // 0..1279
  int bh = blk / UU, u = blk % UU;
  int b = bh >> 3, h = bh & 7;
  int lane = threadIdx.x;
  int idx = Mtop[bh * UU + u];
  int nseg = (idx >> shift) + 1;

  const float* base = Part + (size_t)(bh * UU + u) * nsegmax * PSTRIDE;
  float ms = -1e30f, ls = 0.f;
  if (lane < nseg) { ms = base[lane * PSTRIDE]; ls = base[lane * PSTRIDE + 1]; }
  float M0 = ms;
#pragma unroll
  for (int s = 1; s < 64; s <<= 1) M0 = fmaxf(M0, __shfl_xor(M0, s));
  float e = (lane < nseg) ? __expf(ms - M0) : 0.f;
  float lt = ls * e;
#pragma unroll
  for (int s = 1; s < 64; s <<= 1) lt += __shfl_xor(lt, s);

  __shared__ float ew[64];
  ew[lane] = e;
  __syncthreads();

  float A = 0.f;
  for (int s = 0; s < nseg; s++) {
    const __half* ha = reinterpret_cast<const __half*>(base + s * PSTRIDE + 2);
    A += ew[s] * __half2float(ha[lane]);
  }
  Out[((size_t)((b * LL + idx) * HH + h)) * DD + lane] = A / lt;
}

// ---------------------------------------------------------------------------
// Last-resort fused attention (tiny workspace only).
// ---------------------------------------------------------------------------
__global__ __launch_bounds__(256) void k_attn_fused(
    const float* __restrict__ Q, const float* __restrict__ K,
    const float* __restrict__ V, const int* __restrict__ Mtop,
    float* __restrict__ Out) {
  int j = blockIdx.x;
  int xcd = j & 7, slot = j >> 3;
  int bh = (xcd << 2) | (slot / 40);
  int u = slot % 40;
  int b = bh >> 3, h = bh & 7;
  int idx = Mtop[bh * UU + u];

  int t = threadIdx.x;
  int w = t >> 6, lane = t & 63;
  int kk = lane & 15, gg = lane >> 4;

  __shared__ float Kt[64 * LDK];
  __shared__ float Vt[64 * LDK];
  __shared__ float qs[64];

  const float* qp = Q + ((size_t)((b * LL + idx) * HH + h)) * DD;
  if (t < 64) qs[t] = qp[t] * 0.125f;
  __syncthreads();

  float qr[16];
#pragma unroll
  for (int jj = 0; jj < 16; jj++) qr[jj] = qs[gg * 16 + jj];

  float m = -1e30f, l = 0.f, acc = 0.f;
  int nch = (idx + 64) >> 6;

  for (int ch = 0; ch < nch; ch++) {
    __syncthreads();
    const float4* kg = reinterpret_cast<const float4*>(K + ((size_t)((b * LL + ch * 64) * HH + h)) * DD);
    const float4* vg = reinterpret_cast<const float4*>(V + ((size_t)((b * LL + ch * 64) * HH + h)) * DD);
#pragma unroll
    for (int i = 0; i < 4; i++) {
      int f = t + i * 256;
      int r = f >> 4, col = f & 15;
      float4 kv4 = kg[(size_t)r * (HH * DD / 4) + col];
      float4 vv4 = vg[(size_t)r * (HH * DD / 4) + col];
      *reinterpret_cast<float4*>(&Kt[r * LDK + col * 4]) = kv4;
      *reinterpret_cast<float4*>(&Vt[r * LDK + col * 4]) = vv4;
    }
    __syncthreads();

    int row = w * 16 + kk;
    int key = ch * 64 + row;
    float dp = 0.f;
#pragma unroll
    for (int jj = 0; jj < 4; jj++) {
      float4 kv4 = *reinterpret_cast<const float4*>(&Kt[row * LDK + gg * 16 + jj * 4]);
      dp += qr[jj * 4 + 0] * kv4.x + qr[jj * 4 + 1] * kv4.y +
            qr[jj * 4 + 2] * kv4.z + qr[jj * 4 + 3] * kv4.w;
    }
    dp += __shfl_xor(dp, 16);
    dp += __shfl_xor(dp, 32);
    bool valid = (key <= idx);
    float s = valid ? dp : -1e30f;
    float cm = s;
    cm = fmaxf(cm, __shfl_xor(cm, 1));
    cm = fmaxf(cm, __shfl_xor(cm, 2));
    cm = fmaxf(cm, __shfl_xor(cm, 4));
    cm = fmaxf(cm, __shfl_xor(cm, 8));
    float mn = fmaxf(m, cm);
    float f_ = __expf(m - mn);
    float p = valid ? __expf(s - mn) : 0.f;
    float ps = p;
    ps += __shfl_xor(ps, 1);
    ps += __shfl_xor(ps, 2);
    ps += __shfl_xor(ps, 4);
    ps += __shfl_xor(ps, 8);
    l = l * f_ + ps;
    m = mn;
    acc *= f_;
#pragma unroll
    for (int k2 = 0; k2 < 16; k2++) {
      float pk = __shfl(p, k2);
      acc += pk * Vt[(w * 16 + k2) * LDK + lane];
    }
  }

  __syncthreads();
  float* mw = Kt;
  float* lw = Kt + 8;
  float* aw = Vt;
  if (lane == 0) { mw[w] = m; lw[w] = l; }
  aw[w * 64 + lane] = acc;
  __syncthreads();
  if (w == 0) {
    float M0 = fmaxf(fmaxf(mw[0], mw[1]), fmaxf(mw[2], mw[3]));
    float Lt = 0.f, A = 0.f;
#pragma unroll
    for (int i = 0; i < 4; i++) {
      float e = __expf(mw[i] - M0);
      Lt += lw[i] * e;
      A += aw[i * 64 + lane] * e;
    }
    Out[((size_t)((b * LL + idx) * HH + h)) * DD + lane] = A / Lt;
  }
}

// ---------------------------------------------------------------------------
extern "C" void kernel_launch(void* const* d_in, const int* in_sizes, int n_in,
                              void* d_out, int out_size, void* d_ws, size_t ws_size,
                              hipStream_t stream) {
  const float* Q = (const float*)d_in[0];
  const float* K = (const float*)d_in[1];
  const float* V = (const float*)d_in[2];
  const int* IS = (const int*)d_in[3];
  float* Out = (float*)d_out;

  float* M = (float*)d_ws;                          // 65536 f
  float* CS16 = M + BB * HH * LL;                   // 262144 f
  float* PS16 = CS16 + BB * HH * 128 * DD;          // 262144 f
  int* Mtop = (int*)(PS16 + BB * HH * 128 * DD);    // 1280 i
  float* Part = (float*)(Mtop + BB * HH * UU);
  size_t fixed = (size_t)(BB * HH * LL + 2 * BB * HH * 128 * DD) * 4 +
                 (size_t)(BB * HH * UU) * 4;                      // ~2.37 MB
  size_t need32 = fixed + (size_t)(BB * HH * UU) * NSEG32 * PSTRIDE * 4;  // ~13.5 MB
  size_t need64 = fixed + (size_t)(BB * HH * UU) * NSEG64 * PSTRIDE * 4;  // ~7.9 MB

  k_sample_score<<<16384, 256, 0, stream>>>(Q, K, IS, M);
  k_topk<<<BB * HH, 64, 0, stream>>>(M, Mtop);
  k_chunksum16<<<4096, 64, 0, stream>>>(V, CS16);
  k_prefix16<<<BB * HH, 256, 0, stream>>>(CS16, PS16);
  k_cumsum16<<<4096, 64, 0, stream>>>(V, PS16, Out);
  if (ws_size >= need32) {
    k_attn_part32<<<2048, 256, 0, stream>>>(Q, K, V, Mtop, Part);
    k_attn_merge<<<BB * HH * UU, 64, 0, stream>>>(Mtop, Part, Out, 5, NSEG32);
  } else if (ws_size >= need64) {
    k_attn_part64<<<1024, 256, 0, stream>>>(Q, K, V, Mtop, Part);
    k_attn_merge<<<BB * HH * UU, 64, 0, stream>>>(Mtop, Part, Out, 6, NSEG64);
  } else {
    k_attn_fused<<<BB * HH * UU, 256, 0, stream>>>(Q, K, V, Mtop, Out);
  }
}

// Round 7
// 218.372 us; speedup vs baseline: 1.2689x; 1.2689x over previous
//
#include <hip/hip_runtime.h>
#include <hip/hip_bf16.h>
#include <hip/hip_fp16.h>
#include <cstdint>

// ProbSparse attention (Informer). B=4, L=2048, H=8, D=64, sample_k=u=40.
#define BB 4
#define LL 2048
#define HH 8
#define DD 64
#define SK 40
#define UU 40
#define LDK 68     // LDS row pitch (floats): 68 ≡ 4 mod 32 banks
#define NSEG32 64  // 64 segments of 32 keys (primary path)
#define NSEG64 32  // 32 segments of 64 keys (fallback path)
#define PSTRIDE 34 // Part entry: [f32 m][f32 l][64 x half] = 136 B = 34 floats

// ---------------------------------------------------------------------------
// Kernel 1: M[b,h,q] = max_s(Q·K_s) - mean_s(Q·K_s).
// Block 256 = 32 queries x 8 lanes. Lane sp reads K-row floats [sp*4..+4)
// and [32+sp*4..+4): each instruction = 8 lanes x 16B contiguous 128B
// = 1 L2 transaction -> 2 transactions per query-sample (minimum).
// Q fragment in registers; 3 shfl_xor reduce. Grid 2048 = 8 blocks/CU.
// ---------------------------------------------------------------------------
__global__ __launch_bounds__(256) void k_sample_score(
    const float* __restrict__ Q, const float* __restrict__ K,
    const int* __restrict__ idxs, float* __restrict__ M) {
  int j = blockIdx.x;                 // 0..2047
  int xcd = j & 7, r = j >> 3;        // r 0..255
  int bh = (xcd << 2) | (r >> 6);     // 4 bh per XCD
  int qc = r & 63;                    // 64 q-chunks of 32
  int b = bh >> 3, h = bh & 7;
  int t = threadIdx.x;
  int ql = t >> 3, sp = t & 7;        // 32 queries x 8 sub-parts
  int q = qc * 32 + ql;

  __shared__ int sidx[SK][32];        // transposed sample indices
  for (int i = t; i < SK * 32; i += 256)
    sidx[i >> 5][i & 31] = idxs[(qc * 32 + (i & 31)) * SK + (i >> 5)];
  __syncthreads();

  const float* qrow = Q + ((size_t)((b * LL + q) * HH + h)) * DD;
  float4 qa = *reinterpret_cast<const float4*>(qrow + sp * 4);
  float4 qb = *reinterpret_cast<const float4*>(qrow + 32 + sp * 4);

  const float* kb = K + (size_t)b * (LL * HH * DD) + h * DD;
  float mx = -1e30f, sm = 0.f;
#pragma unroll 4
  for (int s = 0; s < SK; s++) {
    int ks = sidx[s][ql];
    const float* kr = kb + (size_t)ks * (HH * DD);
    float4 ca = *reinterpret_cast<const float4*>(kr + sp * 4);
    float4 cb = *reinterpret_cast<const float4*>(kr + 32 + sp * 4);
    float dot = qa.x * ca.x + qa.y * ca.y + qa.z * ca.z + qa.w * ca.w +
                qb.x * cb.x + qb.y * cb.y + qb.z * cb.z + qb.w * cb.w;
    dot += __shfl_xor(dot, 1);
    dot += __shfl_xor(dot, 2);
    dot += __shfl_xor(dot, 4);        // full dot on all 8 lanes of the group
    mx = fmaxf(mx, dot);
    sm += dot;
  }
  if (sp == 0) M[bh * LL + q] = mx - sm * (1.0f / SK);
}

// ---------------------------------------------------------------------------
// Kernel 2: top-40 of M[b,h,:]. One wave; 32 packed u64 keys/lane in regs.
// key = (ordered_float<<32)|~idx -> max == (max val, lowest idx).
// ---------------------------------------------------------------------------
__global__ __launch_bounds__(64) void k_topk(const float* __restrict__ M,
                                             int* __restrict__ Mtop) {
  int bh = blockIdx.x;
  int lane = threadIdx.x;
  unsigned long long key[32];
  unsigned long long lmax = 0ull;
#pragma unroll
  for (int i = 0; i < 32; i++) {
    int e = i * 64 + lane;
    unsigned u = __float_as_uint(M[bh * LL + e]);
    u = (u & 0x80000000u) ? ~u : (u | 0x80000000u);
    key[i] = ((unsigned long long)u << 32) | (unsigned)(~e);
    lmax = key[i] > lmax ? key[i] : lmax;
  }
  for (int it = 0; it < UU; it++) {
    unsigned long long best = lmax;
#pragma unroll
    for (int s = 1; s < 64; s <<= 1) {
      unsigned long long o = __shfl_xor(best, s);
      best = o > best ? o : best;
    }
    int e = (int)(~(unsigned)best) & (LL - 1);
    if (lane == 0) Mtop[bh * UU + it] = e;
    if ((e & 63) == lane) {
      int slot = e >> 6;
#pragma unroll
      for (int i = 0; i < 32; i++)
        if (i == slot) key[i] = 0ull;
      lmax = 0ull;
#pragma unroll
      for (int i = 0; i < 32; i++) lmax = key[i] > lmax ? key[i] : lmax;
    }
  }
}

// ---------------------------------------------------------------------------
// Cumsum stage A: 16-row chunk sums, vectorized. 64 thr: lane=(d4 0..15,
// r4 0..3); each lane sums 4 rows x float4; cross-r4 reduce via shfl.
// ---------------------------------------------------------------------------
__global__ __launch_bounds__(64) void k_chunksum16(const float* __restrict__ V,
                                                   float* __restrict__ CS16) {
  int j = blockIdx.x;                 // 0..4095
  int xcd = j & 7, r = j >> 3;        // r 0..511
  int bh = (xcd << 2) | (r >> 7);
  int c = r & 127;
  int b = bh >> 3, h = bh & 7;
  int t = threadIdx.x, d4 = t & 15, r4 = t >> 4;
  const float4* vp = reinterpret_cast<const float4*>(
      V + ((size_t)((b * LL + c * 16 + r4 * 4) * HH + h)) * DD) + d4;
  float4 v0 = vp[0], v1 = vp[128], v2 = vp[256], v3 = vp[384];
  float4 s;
  s.x = v0.x + v1.x + v2.x + v3.x;
  s.y = v0.y + v1.y + v2.y + v3.y;
  s.z = v0.z + v1.z + v2.z + v3.z;
  s.w = v0.w + v1.w + v2.w + v3.w;
#pragma unroll
  for (int sh = 16; sh < 64; sh <<= 1) {
    s.x += __shfl_xor(s.x, sh);
    s.y += __shfl_xor(s.y, sh);
    s.z += __shfl_xor(s.z, sh);
    s.w += __shfl_xor(s.w, sh);
  }
  if (r4 == 0)
    *reinterpret_cast<float4*>(CS16 + ((size_t)bh * 128 + c) * 64 + d4 * 4) = s;
}

// ---------------------------------------------------------------------------
// Cumsum stage B: exclusive prefix over 128 chunk-sums per bh.
// ---------------------------------------------------------------------------
__global__ __launch_bounds__(256) void k_prefix16(const float* __restrict__ CS16,
                                                  float* __restrict__ PS16) {
  int bh = blockIdx.x;
  int t = threadIdx.x, w = t >> 6, d = t & 63;
  float cs[32];
  const float* base = CS16 + ((size_t)bh * 128 + w * 32) * 64 + d;
#pragma unroll
  for (int cc = 0; cc < 32; cc++) cs[cc] = base[cc * 64];
  float tot = 0.f;
#pragma unroll
  for (int cc = 0; cc < 32; cc++) tot += cs[cc];
  __shared__ float totw[4][64];
  totw[w][d] = tot;
  __syncthreads();
  float run = 0.f;
#pragma unroll
  for (int w2 = 0; w2 < 4; w2++)
    if (w2 < w) run += totw[w2][d];
  float* pbase = PS16 + ((size_t)bh * 128 + w * 32) * 64 + d;
#pragma unroll
  for (int cc = 0; cc < 32; cc++) { pbase[cc * 64] = run; run += cs[cc]; }
}

// ---------------------------------------------------------------------------
// Cumsum stage C: write Out rows. In-register 4-row prefix + shfl_up scan.
// ---------------------------------------------------------------------------
__global__ __launch_bounds__(64) void k_cumsum16(const float* __restrict__ V,
                                                 const float* __restrict__ PS16,
                                                 float* __restrict__ Out) {
  int j = blockIdx.x;
  int xcd = j & 7, r = j >> 3;
  int bh = (xcd << 2) | (r >> 7);
  int c = r & 127;
  int b = bh >> 3, h = bh & 7;
  int t = threadIdx.x, d4 = t & 15, r4 = t >> 4;
  size_t rowbase = ((size_t)((b * LL + c * 16 + r4 * 4) * HH + h)) * DD;
  const float4* vp = reinterpret_cast<const float4*>(V + rowbase) + d4;
  float4 v0 = vp[0], v1 = vp[128], v2 = vp[256], v3 = vp[384];
  float4 i0 = v0;
  float4 i1 = {i0.x + v1.x, i0.y + v1.y, i0.z + v1.z, i0.w + v1.w};
  float4 i2 = {i1.x + v2.x, i1.y + v2.y, i1.z + v2.z, i1.w + v2.w};
  float4 i3 = {i2.x + v3.x, i2.y + v3.y, i2.z + v3.z, i2.w + v3.w};
  float4 incl = i3;
  float4 u1;
  u1.x = __shfl_up(incl.x, 16); u1.y = __shfl_up(incl.y, 16);
  u1.z = __shfl_up(incl.z, 16); u1.w = __shfl_up(incl.w, 16);
  if (r4 >= 1) { incl.x += u1.x; incl.y += u1.y; incl.z += u1.z; incl.w += u1.w; }
  float4 u2;
  u2.x = __shfl_up(incl.x, 32); u2.y = __shfl_up(incl.y, 32);
  u2.z = __shfl_up(incl.z, 32); u2.w = __shfl_up(incl.w, 32);
  if (r4 >= 2) { incl.x += u2.x; incl.y += u2.y; incl.z += u2.z; incl.w += u2.w; }
  float4 ex = {incl.x - i3.x, incl.y - i3.y, incl.z - i3.z, incl.w - i3.w};
  float4 ps = *reinterpret_cast<const float4*>(
      PS16 + ((size_t)bh * 128 + c) * 64 + d4 * 4);
  float4 base4 = {ps.x + ex.x, ps.y + ex.y, ps.z + ex.z, ps.w + ex.w};
  float4* op = reinterpret_cast<float4*>(Out + rowbase) + d4;
  float4 o;
  o = {base4.x + i0.x, base4.y + i0.y, base4.z + i0.z, base4.w + i0.w}; op[0]   = o;
  o = {base4.x + i1.x, base4.y + i1.y, base4.z + i1.z, base4.w + i1.w}; op[128] = o;
  o = {base4.x + i2.x, base4.y + i2.y, base4.z + i2.z, base4.w + i2.w}; op[256] = o;
  o = {base4.x + i3.x, base4.y + i3.y, base4.z + i3.z, base4.w + i3.w}; op[384] = o;
}

// ---------------------------------------------------------------------------
// Kernel 4a (primary): partial attention, 32-key segments. Block = (bh,seg).
// ---------------------------------------------------------------------------
__global__ __launch_bounds__(256) void k_attn_part32(
    const float* __restrict__ Q, const float* __restrict__ K,
    const float* __restrict__ V, const int* __restrict__ Mtop,
    float* __restrict__ Part) {
  int j = blockIdx.x;                  // 0..2047
  int xcd = j & 7, r_ = j >> 3;        // 0..255
  int bh = (xcd << 2) | (r_ & 3);
  int seg = r_ >> 2;                   // 0..63
  int b = bh >> 3, h = bh & 7;
  int s0 = seg * 32;

  int t = threadIdx.x;
  int w = t >> 6, lane = t & 63;
  int kk = lane & 15, gg = lane >> 4;

  __shared__ float Kt[32 * LDK];
  __shared__ float Vt[32 * LDK];
  __shared__ int midx[UU];

  if (t < UU) midx[t] = Mtop[bh * UU + t];

  const float4* kg = reinterpret_cast<const float4*>(
      K + ((size_t)((b * LL + s0) * HH + h)) * DD);
  const float4* vg = reinterpret_cast<const float4*>(
      V + ((size_t)((b * LL + s0) * HH + h)) * DD);
#pragma unroll
  for (int i = 0; i < 2; i++) {
    int f = t + i * 256;               // 0..511 float4 slots
    int r = f >> 4, col = f & 15;
    float4 kv4 = kg[(size_t)r * (HH * DD / 4) + col];
    float4 vv4 = vg[(size_t)r * (HH * DD / 4) + col];
    *reinterpret_cast<float4*>(&Kt[r * LDK + col * 4]) = kv4;
    *reinterpret_cast<float4*>(&Vt[r * LDK + col * 4]) = vv4;
  }
  __syncthreads();

  for (int uu = 0; uu < 10; uu++) {
    int u = w + uu * 4;
    int idx = midx[u];
    if (idx < s0) continue;            // wave-uniform skip
    int kend = idx - s0;
    if (kend > 31) kend = 31;

    const float4* qv = reinterpret_cast<const float4*>(
        Q + ((size_t)((b * LL + idx) * HH + h)) * DD + gg * 16);
    float4 qr0 = qv[0], qr1 = qv[1], qr2 = qv[2], qr3 = qv[3];

    float m = -1e30f, l = 0.f, acc = 0.f;
#pragma unroll
    for (int ks = 0; ks < 2; ks++) {
      if (ks * 16 > kend) break;       // uniform
      int row = ks * 16 + kk;
      float dp = 0.f;
      const float4* kr = reinterpret_cast<const float4*>(&Kt[row * LDK + gg * 16]);
      float4 c0 = kr[0], c1 = kr[1], c2 = kr[2], c3 = kr[3];
      dp += qr0.x * c0.x + qr0.y * c0.y + qr0.z * c0.z + qr0.w * c0.w;
      dp += qr1.x * c1.x + qr1.y * c1.y + qr1.z * c1.z + qr1.w * c1.w;
      dp += qr2.x * c2.x + qr2.y * c2.y + qr2.z * c2.z + qr2.w * c2.w;
      dp += qr3.x * c3.x + qr3.y * c3.y + qr3.z * c3.z + qr3.w * c3.w;
      dp += __shfl_xor(dp, 16);
      dp += __shfl_xor(dp, 32);
      bool valid = (row <= kend);
      float s = valid ? dp * 0.125f : -1e30f;
      float cm = s;
      cm = fmaxf(cm, __shfl_xor(cm, 1));
      cm = fmaxf(cm, __shfl_xor(cm, 2));
      cm = fmaxf(cm, __shfl_xor(cm, 4));
      cm = fmaxf(cm, __shfl_xor(cm, 8));
      float mn = fmaxf(m, cm);
      float f_ = __expf(m - mn);
      float p = valid ? __expf(s - mn) : 0.f;
      float ps = p;
      ps += __shfl_xor(ps, 1);
      ps += __shfl_xor(ps, 2);
      ps += __shfl_xor(ps, 4);
      ps += __shfl_xor(ps, 8);
      l = l * f_ + ps;
      m = mn;
      acc *= f_;
#pragma unroll
      for (int k2 = 0; k2 < 16; k2++) {
        float pk = __shfl(p, k2);
        acc += pk * Vt[(ks * 16 + k2) * LDK + lane];
      }
    }

    float* pb = Part + ((size_t)(bh * UU + u) * NSEG32 + seg) * PSTRIDE;
    __half* ph = reinterpret_cast<__half*>(pb + 2);
    ph[lane] = __float2half(acc);
    if (lane == 0) { pb[0] = m; pb[1] = l; }
  }
}

// ---------------------------------------------------------------------------
// Kernel 4a (fallback): 64-key segments, same Part layout (stride NSEG64).
// ---------------------------------------------------------------------------
__global__ __launch_bounds__(256) void k_attn_part64(
    const float* __restrict__ Q, const float* __restrict__ K,
    const float* __restrict__ V, const int* __restrict__ Mtop,
    float* __restrict__ Part) {
  int j = blockIdx.x;                  // 0..1023
  int xcd = j & 7, r_ = j >> 3;
  int bh = (xcd << 2) | (r_ & 3);
  int seg = r_ >> 2;                   // 0..31
  int b = bh >> 3, h = bh & 7;
  int s0 = seg * 64;

  int t = threadIdx.x;
  int w = t >> 6, lane = t & 63;
  int kk = lane & 15, gg = lane >> 4;

  __shared__ float Kt[64 * LDK];
  __shared__ float Vt[64 * LDK];
  __shared__ int midx[UU];

  if (t < UU) midx[t] = Mtop[bh * UU + t];

  const float4* kg = reinterpret_cast<const float4*>(
      K + ((size_t)((b * LL + s0) * HH + h)) * DD);
  const float4* vg = reinterpret_cast<const float4*>(
      V + ((size_t)((b * LL + s0) * HH + h)) * DD);
#pragma unroll
  for (int i = 0; i < 4; i++) {
    int f = t + i * 256;
    int r = f >> 4, col = f & 15;
    float4 kv4 = kg[(size_t)r * (HH * DD / 4) + col];
    float4 vv4 = vg[(size_t)r * (HH * DD / 4) + col];
    *reinterpret_cast<float4*>(&Kt[r * LDK + col * 4]) = kv4;
    *reinterpret_cast<float4*>(&Vt[r * LDK + col * 4]) = vv4;
  }
  __syncthreads();

  for (int uu = 0; uu < 10; uu++) {
    int u = w + uu * 4;
    int idx = midx[u];
    if (idx < s0) continue;
    int kend = idx - s0;
    if (kend > 63) kend = 63;

    const float4* qv = reinterpret_cast<const float4*>(
        Q + ((size_t)((b * LL + idx) * HH + h)) * DD + gg * 16);
    float4 qr0 = qv[0], qr1 = qv[1], qr2 = qv[2], qr3 = qv[3];

    float m = -1e30f, l = 0.f, acc = 0.f;
#pragma unroll
    for (int ks = 0; ks < 4; ks++) {
      if (ks * 16 > kend) break;
      int row = ks * 16 + kk;
      float dp = 0.f;
      const float4* kr = reinterpret_cast<const float4*>(&Kt[row * LDK + gg * 16]);
      float4 c0 = kr[0], c1 = kr[1], c2 = kr[2], c3 = kr[3];
      dp += qr0.x * c0.x + qr0.y * c0.y + qr0.z * c0.z + qr0.w * c0.w;
      dp += qr1.x * c1.x + qr1.y * c1.y + qr1.z * c1.z + qr1.w * c1.w;
      dp += qr2.x * c2.x + qr2.y * c2.y + qr2.z * c2.z + qr2.w * c2.w;
      dp += qr3.x * c3.x + qr3.y * c3.y + qr3.z * c3.z + qr3.w * c3.w;
      dp += __shfl_xor(dp, 16);
      dp += __shfl_xor(dp, 32);
      bool valid = (row <= kend);
      float s = valid ? dp * 0.125f : -1e30f;
      float cm = s;
      cm = fmaxf(cm, __shfl_xor(cm, 1));
      cm = fmaxf(cm, __shfl_xor(cm, 2));
      cm = fmaxf(cm, __shfl_xor(cm, 4));
      cm = fmaxf(cm, __shfl_xor(cm, 8));
      float mn = fmaxf(m, cm);
      float f_ = __expf(m - mn);
      float p = valid ? __expf(s - mn) : 0.f;
      float ps = p;
      ps += __shfl_xor(ps, 1);
      ps += __shfl_xor(ps, 2);
      ps += __shfl_xor(ps, 4);
      ps += __shfl_xor(ps, 8);
      l = l * f_ + ps;
      m = mn;
      acc *= f_;
#pragma unroll
      for (int k2 = 0; k2 < 16; k2++) {
        float pk = __shfl(p, k2);
        acc += pk * Vt[(ks * 16 + k2) * LDK + lane];
      }
    }

    float* pb = Part + ((size_t)(bh * UU + u) * NSEG64 + seg) * PSTRIDE;
    __half* ph = reinterpret_cast<__half*>(pb + 2);
    ph[lane] = __float2half(acc);
    if (lane == 0) { pb[0] = m; pb[1] = l; }
  }
}

// ---------------------------------------------------------------------------
// Kernel 4b: merge segment partials per (bh,u).
// ---------------------------------------------------------------------------
__global__ __launch_bounds__(64) void k_attn_merge(
    const int* __restrict__ Mtop, const float* __restrict__ Part,
    float* __restrict__ Out, int shift, int nsegmax) {
  int blk = blockIdx.x;                // 0..1279
  int bh = blk / UU, u = blk % UU;
  int b = bh >> 3, h = bh & 7;
  int lane = threadIdx.x;
  int idx = Mtop[bh * UU + u];
  int nseg = (idx >> shift) + 1;

  const float* base = Part + (size_t)(bh * UU + u) * nsegmax * PSTRIDE;
  float ms = -1e30f, ls = 0.f;
  if (lane < nseg) { ms = base[lane * PSTRIDE]; ls = base[lane * PSTRIDE + 1]; }
  float M0 = ms;
#pragma unroll
  for (int s = 1; s < 64; s <<= 1) M0 = fmaxf(M0, __shfl_xor(M0, s));
  float e = (lane < nseg) ? __expf(ms - M0) : 0.f;
  float lt = ls * e;
#pragma unroll
  for (int s = 1; s < 64; s <<= 1) lt += __shfl_xor(lt, s);

  __shared__ float ew[64];
  ew[lane] = e;
  __syncthreads();

  float A = 0.f;
  for (int s = 0; s < nseg; s++) {
    const __half* ha = reinterpret_cast<const __half*>(base + s * PSTRIDE + 2);
    A += ew[s] * __half2float(ha[lane]);
  }
  Out[((size_t)((b * LL + idx) * HH + h)) * DD + lane] = A / lt;
}

// ---------------------------------------------------------------------------
// Last-resort fused attention (tiny workspace only).
// ---------------------------------------------------------------------------
__global__ __launch_bounds__(256) void k_attn_fused(
    const float* __restrict__ Q, const float* __restrict__ K,
    const float* __restrict__ V, const int* __restrict__ Mtop,
    float* __restrict__ Out) {
  int j = blockIdx.x;
  int xcd = j & 7, slot = j >> 3;
  int bh = (xcd << 2) | (slot / 40);
  int u = slot % 40;
  int b = bh >> 3, h = bh & 7;
  int idx = Mtop[bh * UU + u];

  int t = threadIdx.x;
  int w = t >> 6, lane = t & 63;
  int kk = lane & 15, gg = lane >> 4;

  __shared__ float Kt[64 * LDK];
  __shared__ float Vt[64 * LDK];
  __shared__ float qs[64];

  const float* qp = Q + ((size_t)((b * LL + idx) * HH + h)) * DD;
  if (t < 64) qs[t] = qp[t] * 0.125f;
  __syncthreads();

  float qr[16];
#pragma unroll
  for (int jj = 0; jj < 16; jj++) qr[jj] = qs[gg * 16 + jj];

  float m = -1e30f, l = 0.f, acc = 0.f;
  int nch = (idx + 64) >> 6;

  for (int ch = 0; ch < nch; ch++) {
    __syncthreads();
    const float4* kg = reinterpret_cast<const float4*>(K + ((size_t)((b * LL + ch * 64) * HH + h)) * DD);
    const float4* vg = reinterpret_cast<const float4*>(V + ((size_t)((b * LL + ch * 64) * HH + h)) * DD);
#pragma unroll
    for (int i = 0; i < 4; i++) {
      int f = t + i * 256;
      int r = f >> 4, col = f & 15;
      float4 kv4 = kg[(size_t)r * (HH * DD / 4) + col];
      float4 vv4 = vg[(size_t)r * (HH * DD / 4) + col];
      *reinterpret_cast<float4*>(&Kt[r * LDK + col * 4]) = kv4;
      *reinterpret_cast<float4*>(&Vt[r * LDK + col * 4]) = vv4;
    }
    __syncthreads();

    int row = w * 16 + kk;
    int key = ch * 64 + row;
    float dp = 0.f;
#pragma unroll
    for (int jj = 0; jj < 4; jj++) {
      float4 kv4 = *reinterpret_cast<const float4*>(&Kt[row * LDK + gg * 16 + jj * 4]);
      dp += qr[jj * 4 + 0] * kv4.x + qr[jj * 4 + 1] * kv4.y +
            qr[jj * 4 + 2] * kv4.z + qr[jj * 4 + 3] * kv4.w;
    }
    dp += __shfl_xor(dp, 16);
    dp += __shfl_xor(dp, 32);
    bool valid = (key <= idx);
    float s = valid ? dp : -1e30f;
    float cm = s;
    cm = fmaxf(cm, __shfl_xor(cm, 1));
    cm = fmaxf(cm, __shfl_xor(cm, 2));
    cm = fmaxf(cm, __shfl_xor(cm, 4));
    cm = fmaxf(cm, __shfl_xor(cm, 8));
    float mn = fmaxf(m, cm);
    float f_ = __expf(m - mn);
    float p = valid ? __expf(s - mn) : 0.f;
    float ps = p;
    ps += __shfl_xor(ps, 1);
    ps += __shfl_xor(ps, 2);
    ps += __shfl_xor(ps, 4);
    ps += __shfl_xor(ps, 8);
    l = l * f_ + ps;
    m = mn;
    acc *= f_;
#pragma unroll
    for (int k2 = 0; k2 < 16; k2++) {
      float pk = __shfl(p, k2);
      acc += pk * Vt[(w * 16 + k2) * LDK + lane];
    }
  }

  __syncthreads();
  float* mw = Kt;
  float* lw = Kt + 8;
  float* aw = Vt;
  if (lane == 0) { mw[w] = m; lw[w] = l; }
  aw[w * 64 + lane] = acc;
  __syncthreads();
  if (w == 0) {
    float M0 = fmaxf(fmaxf(mw[0], mw[1]), fmaxf(mw[2], mw[3]));
    float Lt = 0.f, A = 0.f;
#pragma unroll
    for (int i = 0; i < 4; i++) {
      float e = __expf(mw[i] - M0);
      Lt += lw[i] * e;
      A += aw[i * 64 + lane] * e;
    }
    Out[((size_t)((b * LL + idx) * HH + h)) * DD + lane] = A / Lt;
  }
}

// ---------------------------------------------------------------------------
extern "C" void kernel_launch(void* const* d_in, const int* in_sizes, int n_in,
                              void* d_out, int out_size, void* d_ws, size_t ws_size,
                              hipStream_t stream) {
  const float* Q = (const float*)d_in[0];
  const float* K = (const float*)d_in[1];
  const float* V = (const float*)d_in[2];
  const int* IS = (const int*)d_in[3];
  float* Out = (float*)d_out;

  float* M = (float*)d_ws;                          // 65536 f
  float* CS16 = M + BB * HH * LL;                   // 262144 f
  float* PS16 = CS16 + BB * HH * 128 * DD;          // 262144 f
  int* Mtop = (int*)(PS16 + BB * HH * 128 * DD);    // 1280 i
  float* Part = (float*)(Mtop + BB * HH * UU);
  size_t fixed = (size_t)(BB * HH * LL + 2 * BB * HH * 128 * DD) * 4 +
                 (size_t)(BB * HH * UU) * 4;                      // ~2.37 MB
  size_t need32 = fixed + (size_t)(BB * HH * UU) * NSEG32 * PSTRIDE * 4;  // ~13.5 MB
  size_t need64 = fixed + (size_t)(BB * HH * UU) * NSEG64 * PSTRIDE * 4;  // ~7.9 MB

  k_sample_score<<<2048, 256, 0, stream>>>(Q, K, IS, M);
  k_topk<<<BB * HH, 64, 0, stream>>>(M, Mtop);
  k_chunksum16<<<4096, 64, 0, stream>>>(V, CS16);
  k_prefix16<<<BB * HH, 256, 0, stream>>>(CS16, PS16);
  k_cumsum16<<<4096, 64, 0, stream>>>(V, PS16, Out);
  if (ws_size >= need32) {
    k_attn_part32<<<2048, 256, 0, stream>>>(Q, K, V, Mtop, Part);
    k_attn_merge<<<BB * HH * UU, 64, 0, stream>>>(Mtop, Part, Out, 5, NSEG32);
  } else if (ws_size >= need64) {
    k_attn_part64<<<1024, 256, 0, stream>>>(Q, K, V, Mtop, Part);
    k_attn_merge<<<BB * HH * UU, 64, 0, stream>>>(Mtop, Part, Out, 6, NSEG64);
  } else {
    k_attn_fused<<<BB * HH * UU, 256, 0, stream>>>(Q, K, V, Mtop, Out);
  }
}

// Round 8
// 195.810 us; speedup vs baseline: 1.4151x; 1.1152x over previous
//
#include <hip/hip_runtime.h>
#include <hip/hip_bf16.h>
#include <hip/hip_fp16.h>
#include <cstdint>

// ProbSparse attention (Informer). B=4, L=2048, H=8, D=64, sample_k=u=40.
#define BB 4
#define LL 2048
#define HH 8
#define DD 64
#define SK 40
#define UU 40
#define LDK 68     // LDS row pitch (floats): 68 ≡ 4 mod 32 banks
#define NSEG32 64  // 64 segments of 32 keys (primary path)
#define NSEG64 32  // 32 segments of 64 keys (fallback path)
#define PSTRIDE 34 // Part entry: [f32 m][f32 l][64 x half] = 136 B = 34 floats

// ---------------------------------------------------------------------------
// Kernel 1: M[b,h,q] = max_s(Q·K_s) - mean_s(Q·K_s).
// Block 256 = 32 queries x 8 lanes; lane sp reads K-row floats [sp*4..+4)
// and [32+sp*4..+4): 8 lanes x 16B = 1 contiguous 128B L2 line per instr.
// ---------------------------------------------------------------------------
__global__ __launch_bounds__(256) void k_sample_score(
    const float* __restrict__ Q, const float* __restrict__ K,
    const int* __restrict__ idxs, float* __restrict__ M) {
  int j = blockIdx.x;                 // 0..2047
  int xcd = j & 7, r = j >> 3;        // r 0..255
  int bh = (xcd << 2) | (r >> 6);     // 4 bh per XCD
  int qc = r & 63;                    // 64 q-chunks of 32
  int b = bh >> 3, h = bh & 7;
  int t = threadIdx.x;
  int ql = t >> 3, sp = t & 7;        // 32 queries x 8 sub-parts
  int q = qc * 32 + ql;

  __shared__ int sidx[SK][32];        // transposed sample indices
  for (int i = t; i < SK * 32; i += 256)
    sidx[i >> 5][i & 31] = idxs[(qc * 32 + (i & 31)) * SK + (i >> 5)];
  __syncthreads();

  const float* qrow = Q + ((size_t)((b * LL + q) * HH + h)) * DD;
  float4 qa = *reinterpret_cast<const float4*>(qrow + sp * 4);
  float4 qb = *reinterpret_cast<const float4*>(qrow + 32 + sp * 4);

  const float* kb = K + (size_t)b * (LL * HH * DD) + h * DD;
  float mx = -1e30f, sm = 0.f;
#pragma unroll 4
  for (int s = 0; s < SK; s++) {
    int ks = sidx[s][ql];
    const float* kr = kb + (size_t)ks * (HH * DD);
    float4 ca = *reinterpret_cast<const float4*>(kr + sp * 4);
    float4 cb = *reinterpret_cast<const float4*>(kr + 32 + sp * 4);
    float dot = qa.x * ca.x + qa.y * ca.y + qa.z * ca.z + qa.w * ca.w +
                qb.x * cb.x + qb.y * cb.y + qb.z * cb.z + qb.w * cb.w;
    dot += __shfl_xor(dot, 1);
    dot += __shfl_xor(dot, 2);
    dot += __shfl_xor(dot, 4);
    mx = fmaxf(mx, dot);
    sm += dot;
  }
  if (sp == 0) M[bh * LL + q] = mx - sm * (1.0f / SK);
}

// ---------------------------------------------------------------------------
// Kernel 2: top-40 of M[b,h,:]. One wave; 32 packed u64 keys/lane in regs.
// ---------------------------------------------------------------------------
__global__ __launch_bounds__(64) void k_topk(const float* __restrict__ M,
                                             int* __restrict__ Mtop) {
  int bh = blockIdx.x;
  int lane = threadIdx.x;
  unsigned long long key[32];
  unsigned long long lmax = 0ull;
#pragma unroll
  for (int i = 0; i < 32; i++) {
    int e = i * 64 + lane;
    unsigned u = __float_as_uint(M[bh * LL + e]);
    u = (u & 0x80000000u) ? ~u : (u | 0x80000000u);
    key[i] = ((unsigned long long)u << 32) | (unsigned)(~e);
    lmax = key[i] > lmax ? key[i] : lmax;
  }
  for (int it = 0; it < UU; it++) {
    unsigned long long best = lmax;
#pragma unroll
    for (int s = 1; s < 64; s <<= 1) {
      unsigned long long o = __shfl_xor(best, s);
      best = o > best ? o : best;
    }
    int e = (int)(~(unsigned)best) & (LL - 1);
    if (lane == 0) Mtop[bh * UU + it] = e;
    if ((e & 63) == lane) {
      int slot = e >> 6;
#pragma unroll
      for (int i = 0; i < 32; i++)
        if (i == slot) key[i] = 0ull;
      lmax = 0ull;
#pragma unroll
      for (int i = 0; i < 32; i++) lmax = key[i] > lmax ? key[i] : lmax;
    }
  }
}

// ---------------------------------------------------------------------------
// Cumsum stage A: 16-row chunk sums, vectorized.
// ---------------------------------------------------------------------------
__global__ __launch_bounds__(64) void k_chunksum16(const float* __restrict__ V,
                                                   float* __restrict__ CS16) {
  int j = blockIdx.x;                 // 0..4095
  int xcd = j & 7, r = j >> 3;        // r 0..511
  int bh = (xcd << 2) | (r >> 7);
  int c = r & 127;
  int b = bh >> 3, h = bh & 7;
  int t = threadIdx.x, d4 = t & 15, r4 = t >> 4;
  const float4* vp = reinterpret_cast<const float4*>(
      V + ((size_t)((b * LL + c * 16 + r4 * 4) * HH + h)) * DD) + d4;
  float4 v0 = vp[0], v1 = vp[128], v2 = vp[256], v3 = vp[384];
  float4 s;
  s.x = v0.x + v1.x + v2.x + v3.x;
  s.y = v0.y + v1.y + v2.y + v3.y;
  s.z = v0.z + v1.z + v2.z + v3.z;
  s.w = v0.w + v1.w + v2.w + v3.w;
#pragma unroll
  for (int sh = 16; sh < 64; sh <<= 1) {
    s.x += __shfl_xor(s.x, sh);
    s.y += __shfl_xor(s.y, sh);
    s.z += __shfl_xor(s.z, sh);
    s.w += __shfl_xor(s.w, sh);
  }
  if (r4 == 0)
    *reinterpret_cast<float4*>(CS16 + ((size_t)bh * 128 + c) * 64 + d4 * 4) = s;
}

// ---------------------------------------------------------------------------
// Cumsum stage B: exclusive prefix over 128 chunk-sums per bh.
// ---------------------------------------------------------------------------
__global__ __launch_bounds__(256) void k_prefix16(const float* __restrict__ CS16,
                                                  float* __restrict__ PS16) {
  int bh = blockIdx.x;
  int t = threadIdx.x, w = t >> 6, d = t & 63;
  float cs[32];
  const float* base = CS16 + ((size_t)bh * 128 + w * 32) * 64 + d;
#pragma unroll
  for (int cc = 0; cc < 32; cc++) cs[cc] = base[cc * 64];
  float tot = 0.f;
#pragma unroll
  for (int cc = 0; cc < 32; cc++) tot += cs[cc];
  __shared__ float totw[4][64];
  totw[w][d] = tot;
  __syncthreads();
  float run = 0.f;
#pragma unroll
  for (int w2 = 0; w2 < 4; w2++)
    if (w2 < w) run += totw[w2][d];
  float* pbase = PS16 + ((size_t)bh * 128 + w * 32) * 64 + d;
#pragma unroll
  for (int cc = 0; cc < 32; cc++) { pbase[cc * 64] = run; run += cs[cc]; }
}

// ---------------------------------------------------------------------------
// Cumsum stage C: write Out rows. In-register 4-row prefix + shfl_up scan.
// ---------------------------------------------------------------------------
__global__ __launch_bounds__(64) void k_cumsum16(const float* __restrict__ V,
                                                 const float* __restrict__ PS16,
                                                 float* __restrict__ Out) {
  int j = blockIdx.x;
  int xcd = j & 7, r = j >> 3;
  int bh = (xcd << 2) | (r >> 7);
  int c = r & 127;
  int b = bh >> 3, h = bh & 7;
  int t = threadIdx.x, d4 = t & 15, r4 = t >> 4;
  size_t rowbase = ((size_t)((b * LL + c * 16 + r4 * 4) * HH + h)) * DD;
  const float4* vp = reinterpret_cast<const float4*>(V + rowbase) + d4;
  float4 v0 = vp[0], v1 = vp[128], v2 = vp[256], v3 = vp[384];
  float4 i0 = v0;
  float4 i1 = {i0.x + v1.x, i0.y + v1.y, i0.z + v1.z, i0.w + v1.w};
  float4 i2 = {i1.x + v2.x, i1.y + v2.y, i1.z + v2.z, i1.w + v2.w};
  float4 i3 = {i2.x + v3.x, i2.y + v3.y, i2.z + v3.z, i2.w + v3.w};
  float4 incl = i3;
  float4 u1;
  u1.x = __shfl_up(incl.x, 16); u1.y = __shfl_up(incl.y, 16);
  u1.z = __shfl_up(incl.z, 16); u1.w = __shfl_up(incl.w, 16);
  if (r4 >= 1) { incl.x += u1.x; incl.y += u1.y; incl.z += u1.z; incl.w += u1.w; }
  float4 u2;
  u2.x = __shfl_up(incl.x, 32); u2.y = __shfl_up(incl.y, 32);
  u2.z = __shfl_up(incl.z, 32); u2.w = __shfl_up(incl.w, 32);
  if (r4 >= 2) { incl.x += u2.x; incl.y += u2.y; incl.z += u2.z; incl.w += u2.w; }
  float4 ex = {incl.x - i3.x, incl.y - i3.y, incl.z - i3.z, incl.w - i3.w};
  float4 ps = *reinterpret_cast<const float4*>(
      PS16 + ((size_t)bh * 128 + c) * 64 + d4 * 4);
  float4 base4 = {ps.x + ex.x, ps.y + ex.y, ps.z + ex.z, ps.w + ex.w};
  float4* op = reinterpret_cast<float4*>(Out + rowbase) + d4;
  float4 o;
  o = {base4.x + i0.x, base4.y + i0.y, base4.z + i0.z, base4.w + i0.w}; op[0]   = o;
  o = {base4.x + i1.x, base4.y + i1.y, base4.z + i1.z, base4.w + i1.w}; op[128] = o;
  o = {base4.x + i2.x, base4.y + i2.y, base4.z + i2.z, base4.w + i2.w}; op[256] = o;
  o = {base4.x + i3.x, base4.y + i3.y, base4.z + i3.z, base4.w + i3.w}; op[384] = o;
}

// ---------------------------------------------------------------------------
// Kernel 4a (primary): partial attention, 32-key segments. Block = (bh,seg).
// One-shot segment softmax (no online update); P broadcast via tiny LDS
// array (not shfl); V segment cached in registers (lane = d). K tile only
// in LDS (~9 KB).
// ---------------------------------------------------------------------------
__global__ __launch_bounds__(256) void k_attn_part32(
    const float* __restrict__ Q, const float* __restrict__ K,
    const float* __restrict__ V, const int* __restrict__ Mtop,
    float* __restrict__ Part) {
  int j = blockIdx.x;                  // 0..2047
  int xcd = j & 7, r_ = j >> 3;        // 0..255
  int bh = (xcd << 2) | (r_ & 3);
  int seg = r_ >> 2;                   // 0..63
  int b = bh >> 3, h = bh & 7;
  int s0 = seg * 32;

  int t = threadIdx.x;
  int w = t >> 6, lane = t & 63;
  int kk = lane & 15, gg = lane >> 4;

  __shared__ float Kt[32 * LDK];
  __shared__ float psh[4][32];
  __shared__ int midx[UU];

  if (t < UU) midx[t] = Mtop[bh * UU + t];

  // stage K segment (32 rows x 64 f) into LDS
  const float4* kg = reinterpret_cast<const float4*>(
      K + ((size_t)((b * LL + s0) * HH + h)) * DD);
#pragma unroll
  for (int i = 0; i < 2; i++) {
    int f = t + i * 256;               // 0..511 float4 slots
    int r = f >> 4, col = f & 15;
    float4 kv4 = kg[(size_t)r * (HH * DD / 4) + col];
    *reinterpret_cast<float4*>(&Kt[r * LDK + col * 4]) = kv4;
  }

  // V segment into registers: lane = d, 32 coalesced 256B row loads
  const float* vgp = V + ((size_t)((b * LL + s0) * HH + h)) * DD + lane;
  float vreg[32];
#pragma unroll
  for (int k = 0; k < 32; k++) vreg[k] = vgp[(size_t)k * (HH * DD)];

  __syncthreads();

  for (int uu = 0; uu < 10; uu++) {
    int u = w + uu * 4;
    int idx = midx[u];
    if (idx < s0) continue;            // wave-uniform skip
    int kend = idx - s0;
    if (kend > 31) kend = 31;

    const float4* qv = reinterpret_cast<const float4*>(
        Q + ((size_t)((b * LL + idx) * HH + h)) * DD + gg * 16);
    float4 qr0 = qv[0], qr1 = qv[1], qr2 = qv[2], qr3 = qv[3];

    // scores for rows kk and 16+kk (each replicated across the 4 gg lanes)
    float s0v, s1v;
    {
      const float4* kr = reinterpret_cast<const float4*>(&Kt[kk * LDK + gg * 16]);
      float4 c0 = kr[0], c1 = kr[1], c2 = kr[2], c3 = kr[3];
      float dp = qr0.x * c0.x + qr0.y * c0.y + qr0.z * c0.z + qr0.w * c0.w +
                 qr1.x * c1.x + qr1.y * c1.y + qr1.z * c1.z + qr1.w * c1.w +
                 qr2.x * c2.x + qr2.y * c2.y + qr2.z * c2.z + qr2.w * c2.w +
                 qr3.x * c3.x + qr3.y * c3.y + qr3.z * c3.z + qr3.w * c3.w;
      dp += __shfl_xor(dp, 16);
      dp += __shfl_xor(dp, 32);
      s0v = (kk <= kend) ? dp * 0.125f : -1e30f;
    }
    {
      const float4* kr = reinterpret_cast<const float4*>(&Kt[(16 + kk) * LDK + gg * 16]);
      float4 c0 = kr[0], c1 = kr[1], c2 = kr[2], c3 = kr[3];
      float dp = qr0.x * c0.x + qr0.y * c0.y + qr0.z * c0.z + qr0.w * c0.w +
                 qr1.x * c1.x + qr1.y * c1.y + qr1.z * c1.z + qr1.w * c1.w +
                 qr2.x * c2.x + qr2.y * c2.y + qr2.z * c2.z + qr2.w * c2.w +
                 qr3.x * c3.x + qr3.y * c3.y + qr3.z * c3.z + qr3.w * c3.w;
      dp += __shfl_xor(dp, 16);
      dp += __shfl_xor(dp, 32);
      s1v = (16 + kk <= kend) ? dp * 0.125f : -1e30f;
    }

    // one-shot segment softmax: max + sum reduce over the 16 kk lanes
    float m = fmaxf(s0v, s1v);
    m = fmaxf(m, __shfl_xor(m, 1));
    m = fmaxf(m, __shfl_xor(m, 2));
    m = fmaxf(m, __shfl_xor(m, 4));
    m = fmaxf(m, __shfl_xor(m, 8));
    float p0 = (kk <= kend) ? __expf(s0v - m) : 0.f;
    float p1 = (16 + kk <= kend) ? __expf(s1v - m) : 0.f;
    float l = p0 + p1;
    l += __shfl_xor(l, 1);
    l += __shfl_xor(l, 2);
    l += __shfl_xor(l, 4);
    l += __shfl_xor(l, 8);

    // publish P to per-wave LDS row (same-wave write->read, no barrier)
    if (gg == 0) { psh[w][kk] = p0; psh[w][16 + kk] = p1; }

    // PV: 8 x float4 broadcast reads of P, V in registers
    float acc = 0.f;
#pragma unroll
    for (int kq = 0; kq < 8; kq++) {
      float4 pp = *reinterpret_cast<const float4*>(&psh[w][kq * 4]);
      acc += pp.x * vreg[kq * 4 + 0] + pp.y * vreg[kq * 4 + 1] +
             pp.z * vreg[kq * 4 + 2] + pp.w * vreg[kq * 4 + 3];
    }

    float* pb = Part + ((size_t)(bh * UU + u) * NSEG32 + seg) * PSTRIDE;
    __half* ph = reinterpret_cast<__half*>(pb + 2);
    ph[lane] = __float2half(acc);
    if (lane == 0) { pb[0] = m; pb[1] = l; }
  }
}

// ---------------------------------------------------------------------------
// Kernel 4a (fallback): 64-key segments (unchanged R4-style).
// ---------------------------------------------------------------------------
__global__ __launch_bounds__(256) void k_attn_part64(
    const float* __restrict__ Q, const float* __restrict__ K,
    const float* __restrict__ V, const int* __restrict__ Mtop,
    float* __restrict__ Part) {
  int j = blockIdx.x;                  // 0..1023
  int xcd = j & 7, r_ = j >> 3;
  int bh = (xcd << 2) | (r_ & 3);
  int seg = r_ >> 2;                   // 0..31
  int b = bh >> 3, h = bh & 7;
  int s0 = seg * 64;

  int t = threadIdx.x;
  int w = t >> 6, lane = t & 63;
  int kk = lane & 15, gg = lane >> 4;

  __shared__ float Kt[64 * LDK];
  __shared__ float Vt[64 * LDK];
  __shared__ int midx[UU];

  if (t < UU) midx[t] = Mtop[bh * UU + t];

  const float4* kg = reinterpret_cast<const float4*>(
      K + ((size_t)((b * LL + s0) * HH + h)) * DD);
  const float4* vg = reinterpret_cast<const float4*>(
      V + ((size_t)((b * LL + s0) * HH + h)) * DD);
#pragma unroll
  for (int i = 0; i < 4; i++) {
    int f = t + i * 256;
    int r = f >> 4, col = f & 15;
    float4 kv4 = kg[(size_t)r * (HH * DD / 4) + col];
    float4 vv4 = vg[(size_t)r * (HH * DD / 4) + col];
    *reinterpret_cast<float4*>(&Kt[r * LDK + col * 4]) = kv4;
    *reinterpret_cast<float4*>(&Vt[r * LDK + col * 4]) = vv4;
  }
  __syncthreads();

  for (int uu = 0; uu < 10; uu++) {
    int u = w + uu * 4;
    int idx = midx[u];
    if (idx < s0) continue;
    int kend = idx - s0;
    if (kend > 63) kend = 63;

    const float4* qv = reinterpret_cast<const float4*>(
        Q + ((size_t)((b * LL + idx) * HH + h)) * DD + gg * 16);
    float4 qr0 = qv[0], qr1 = qv[1], qr2 = qv[2], qr3 = qv[3];

    float m = -1e30f, l = 0.f, acc = 0.f;
#pragma unroll
    for (int ks = 0; ks < 4; ks++) {
      if (ks * 16 > kend) break;
      int row = ks * 16 + kk;
      float dp = 0.f;
      const float4* kr = reinterpret_cast<const float4*>(&Kt[row * LDK + gg * 16]);
      float4 c0 = kr[0], c1 = kr[1], c2 = kr[2], c3 = kr[3];
      dp += qr0.x * c0.x + qr0.y * c0.y + qr0.z * c0.z + qr0.w * c0.w;
      dp += qr1.x * c1.x + qr1.y * c1.y + qr1.z * c1.z + qr1.w * c1.w;
      dp += qr2.x * c2.x + qr2.y * c2.y + qr2.z * c2.z + qr2.w * c2.w;
      dp += qr3.x * c3.x + qr3.y * c3.y + qr3.z * c3.z + qr3.w * c3.w;
      dp += __shfl_xor(dp, 16);
      dp += __shfl_xor(dp, 32);
      bool valid = (row <= kend);
      float s = valid ? dp * 0.125f : -1e30f;
      float cm = s;
      cm = fmaxf(cm, __shfl_xor(cm, 1));
      cm = fmaxf(cm, __shfl_xor(cm, 2));
      cm = fmaxf(cm, __shfl_xor(cm, 4));
      cm = fmaxf(cm, __shfl_xor(cm, 8));
      float mn = fmaxf(m, cm);
      float f_ = __expf(m - mn);
      float p = valid ? __expf(s - mn) : 0.f;
      float ps = p;
      ps += __shfl_xor(ps, 1);
      ps += __shfl_xor(ps, 2);
      ps += __shfl_xor(ps, 4);
      ps += __shfl_xor(ps, 8);
      l = l * f_ + ps;
      m = mn;
      acc *= f_;
#pragma unroll
      for (int k2 = 0; k2 < 16; k2++) {
        float pk = __shfl(p, k2);
        acc += pk * Vt[(ks * 16 + k2) * LDK + lane];
      }
    }

    float* pb = Part + ((size_t)(bh * UU + u) * NSEG64 + seg) * PSTRIDE;
    __half* ph = reinterpret_cast<__half*>(pb + 2);
    ph[lane] = __float2half(acc);
    if (lane == 0) { pb[0] = m; pb[1] = l; }
  }
}

// ---------------------------------------------------------------------------
// Kernel 4b: merge segment partials per (bh,u).
// ---------------------------------------------------------------------------
__global__ __launch_bounds__(64) void k_attn_merge(
    const int* __restrict__ Mtop, const float* __restrict__ Part,
    float* __restrict__ Out, int shift, int nsegmax) {
  int blk = blockIdx.x;                // 0..1279
  int bh = blk / UU, u = blk % UU;
  int b = bh >> 3, h = bh & 7;
  int lane = threadIdx.x;
  int idx = Mtop[bh * UU + u];
  int nseg = (idx >> shift) + 1;

  const float* base = Part + (size_t)(bh * UU + u) * nsegmax * PSTRIDE;
  float ms = -1e30f, ls = 0.f;
  if (lane < nseg) { ms = base[lane * PSTRIDE]; ls = base[lane * PSTRIDE + 1]; }
  float M0 = ms;
#pragma unroll
  for (int s = 1; s < 64; s <<= 1) M0 = fmaxf(M0, __shfl_xor(M0, s));
  float e = (lane < nseg) ? __expf(ms - M0) : 0.f;
  float lt = ls * e;
#pragma unroll
  for (int s = 1; s < 64; s <<= 1) lt += __shfl_xor(lt, s);

  __shared__ float ew[64];
  ew[lane] = e;
  __syncthreads();

  float A = 0.f;
  for (int s = 0; s < nseg; s++) {
    const __half* ha = reinterpret_cast<const __half*>(base + s * PSTRIDE + 2);
    A += ew[s] * __half2float(ha[lane]);
  }
  Out[((size_t)((b * LL + idx) * HH + h)) * DD + lane] = A / lt;
}

// ---------------------------------------------------------------------------
// Last-resort fused attention (tiny workspace only).
// ---------------------------------------------------------------------------
__global__ __launch_bounds__(256) void k_attn_fused(
    const float* __restrict__ Q, const float* __restrict__ K,
    const float* __restrict__ V, const int* __restrict__ Mtop,
    float* __restrict__ Out) {
  int j = blockIdx.x;
  int xcd = j & 7, slot = j >> 3;
  int bh = (xcd << 2) | (slot / 40);
  int u = slot % 40;
  int b = bh >> 3, h = bh & 7;
  int idx = Mtop[bh * UU + u];

  int t = threadIdx.x;
  int w = t >> 6, lane = t & 63;
  int kk = lane & 15, gg = lane >> 4;

  __shared__ float Kt[64 * LDK];
  __shared__ float Vt[64 * LDK];
  __shared__ float qs[64];

  const float* qp = Q + ((size_t)((b * LL + idx) * HH + h)) * DD;
  if (t < 64) qs[t] = qp[t] * 0.125f;
  __syncthreads();

  float qr[16];
#pragma unroll
  for (int jj = 0; jj < 16; jj++) qr[jj] = qs[gg * 16 + jj];

  float m = -1e30f, l = 0.f, acc = 0.f;
  int nch = (idx + 64) >> 6;

  for (int ch = 0; ch < nch; ch++) {
    __syncthreads();
    const float4* kg = reinterpret_cast<const float4*>(K + ((size_t)((b * LL + ch * 64) * HH + h)) * DD);
    const float4* vg = reinterpret_cast<const float4*>(V + ((size_t)((b * LL + ch * 64) * HH + h)) * DD);
#pragma unroll
    for (int i = 0; i < 4; i++) {
      int f = t + i * 256;
      int r = f >> 4, col = f & 15;
      float4 kv4 = kg[(size_t)r * (HH * DD / 4) + col];
      float4 vv4 = vg[(size_t)r * (HH * DD / 4) + col];
      *reinterpret_cast<float4*>(&Kt[r * LDK + col * 4]) = kv4;
      *reinterpret_cast<float4*>(&Vt[r * LDK + col * 4]) = vv4;
    }
    __syncthreads();

    int row = w * 16 + kk;
    int key = ch * 64 + row;
    float dp = 0.f;
#pragma unroll
    for (int jj = 0; jj < 4; jj++) {
      float4 kv4 = *reinterpret_cast<const float4*>(&Kt[row * LDK + gg * 16 + jj * 4]);
      dp += qr[jj * 4 + 0] * kv4.x + qr[jj * 4 + 1] * kv4.y +
            qr[jj * 4 + 2] * kv4.z + qr[jj * 4 + 3] * kv4.w;
    }
    dp += __shfl_xor(dp, 16);
    dp += __shfl_xor(dp, 32);
    bool valid = (key <= idx);
    float s = valid ? dp : -1e30f;
    float cm = s;
    cm = fmaxf(cm, __shfl_xor(cm, 1));
    cm = fmaxf(cm, __shfl_xor(cm, 2));
    cm = fmaxf(cm, __shfl_xor(cm, 4));
    cm = fmaxf(cm, __shfl_xor(cm, 8));
    float mn = fmaxf(m, cm);
    float f_ = __expf(m - mn);
    float p = valid ? __expf(s - mn) : 0.f;
    float ps = p;
    ps += __shfl_xor(ps, 1);
    ps += __shfl_xor(ps, 2);
    ps += __shfl_xor(ps, 4);
    ps += __shfl_xor(ps, 8);
    l = l * f_ + ps;
    m = mn;
    acc *= f_;
#pragma unroll
    for (int k2 = 0; k2 < 16; k2++) {
      float pk = __shfl(p, k2);
      acc += pk * Vt[(w * 16 + k2) * LDK + lane];
    }
  }

  __syncthreads();
  float* mw = Kt;
  float* lw = Kt + 8;
  float* aw = Vt;
  if (lane == 0) { mw[w] = m; lw[w] = l; }
  aw[w * 64 + lane] = acc;
  __syncthreads();
  if (w == 0) {
    float M0 = fmaxf(fmaxf(mw[0], mw[1]), fmaxf(mw[2], mw[3]));
    float Lt = 0.f, A = 0.f;
#pragma unroll
    for (int i = 0; i < 4; i++) {
      float e = __expf(mw[i] - M0);
      Lt += lw[i] * e;
      A += aw[i * 64 + lane] * e;
    }
    Out[((size_t)((b * LL + idx) * HH + h)) * DD + lane] = A / Lt;
  }
}

// ---------------------------------------------------------------------------
extern "C" void kernel_launch(void* const* d_in, const int* in_sizes, int n_in,
                              void* d_out, int out_size, void* d_ws, size_t ws_size,
                              hipStream_t stream) {
  const float* Q = (const float*)d_in[0];
  const float* K = (const float*)d_in[1];
  const float* V = (const float*)d_in[2];
  const int* IS = (const int*)d_in[3];
  float* Out = (float*)d_out;

  float* M = (float*)d_ws;                          // 65536 f
  float* CS16 = M + BB * HH * LL;                   // 262144 f
  float* PS16 = CS16 + BB * HH * 128 * DD;          // 262144 f
  int* Mtop = (int*)(PS16 + BB * HH * 128 * DD);    // 1280 i
  float* Part = (float*)(Mtop + BB * HH * UU);
  size_t fixed = (size_t)(BB * HH * LL + 2 * BB * HH * 128 * DD) * 4 +
                 (size_t)(BB * HH * UU) * 4;                      // ~2.37 MB
  size_t need32 = fixed + (size_t)(BB * HH * UU) * NSEG32 * PSTRIDE * 4;  // ~13.5 MB
  size_t need64 = fixed + (size_t)(BB * HH * UU) * NSEG64 * PSTRIDE * 4;  // ~7.9 MB

  k_sample_score<<<2048, 256, 0, stream>>>(Q, K, IS, M);
  k_topk<<<BB * HH, 64, 0, stream>>>(M, Mtop);
  k_chunksum16<<<4096, 64, 0, stream>>>(V, CS16);
  k_prefix16<<<BB * HH, 256, 0, stream>>>(CS16, PS16);
  k_cumsum16<<<4096, 64, 0, stream>>>(V, PS16, Out);
  if (ws_size >= need32) {
    k_attn_part32<<<2048, 256, 0, stream>>>(Q, K, V, Mtop, Part);
    k_attn_merge<<<BB * HH * UU, 64, 0, stream>>>(Mtop, Part, Out, 5, NSEG32);
  } else if (ws_size >= need64) {
    k_attn_part64<<<1024, 256, 0, stream>>>(Q, K, V, Mtop, Part);
    k_attn_merge<<<BB * HH * UU, 64, 0, stream>>>(Mtop, Part, Out, 6, NSEG64);
  } else {
    k_attn_fused<<<BB * HH * UU, 256, 0, stream>>>(Q, K, V, Mtop, Out);
  }
}

// Round 9
// 181.351 us; speedup vs baseline: 1.5279x; 1.0797x over previous
//
#include <hip/hip_runtime.h>
#include <hip/hip_bf16.h>
#include <hip/hip_fp16.h>
#include <cstdint>

// ProbSparse attention (Informer). B=4, L=2048, H=8, D=64, sample_k=u=40.
#define BB 4
#define LL 2048
#define HH 8
#define DD 64
#define SK 40
#define UU 40
#define LDK 68     // LDS row pitch (floats): 68 ≡ 4 mod 32 banks
#define NSEG32 64  // 64 segments of 32 keys (primary path)
#define NSEG64 32  // 32 segments of 64 keys (fallback path)
#define PSTRIDE 34 // Part entry: [f32 m][f32 l][64 x half] = 136 B = 34 floats

// ---------------------------------------------------------------------------
// Kernel 1: M[b,h,q] = max_s(Q·K_s) - mean_s(Q·K_s).
// Block 256 = 32 queries x 8 lanes; lane sp reads K-row floats [sp*4..+4)
// and [32+sp*4..+4): 8 lanes x 16B = 1 contiguous 128B L2 line per instr.
// ---------------------------------------------------------------------------
__global__ __launch_bounds__(256) void k_sample_score(
    const float* __restrict__ Q, const float* __restrict__ K,
    const int* __restrict__ idxs, float* __restrict__ M) {
  int j = blockIdx.x;                 // 0..2047
  int xcd = j & 7, r = j >> 3;        // r 0..255
  int bh = (xcd << 2) | (r >> 6);     // 4 bh per XCD
  int qc = r & 63;                    // 64 q-chunks of 32
  int b = bh >> 3, h = bh & 7;
  int t = threadIdx.x;
  int ql = t >> 3, sp = t & 7;        // 32 queries x 8 sub-parts
  int q = qc * 32 + ql;

  __shared__ int sidx[SK][32];        // transposed sample indices
  for (int i = t; i < SK * 32; i += 256)
    sidx[i >> 5][i & 31] = idxs[(qc * 32 + (i & 31)) * SK + (i >> 5)];
  __syncthreads();

  const float* qrow = Q + ((size_t)((b * LL + q) * HH + h)) * DD;
  float4 qa = *reinterpret_cast<const float4*>(qrow + sp * 4);
  float4 qb = *reinterpret_cast<const float4*>(qrow + 32 + sp * 4);

  const float* kb = K + (size_t)b * (LL * HH * DD) + h * DD;
  float mx = -1e30f, sm = 0.f;
#pragma unroll 4
  for (int s = 0; s < SK; s++) {
    int ks = sidx[s][ql];
    const float* kr = kb + (size_t)ks * (HH * DD);
    float4 ca = *reinterpret_cast<const float4*>(kr + sp * 4);
    float4 cb = *reinterpret_cast<const float4*>(kr + 32 + sp * 4);
    float dot = qa.x * ca.x + qa.y * ca.y + qa.z * ca.z + qa.w * ca.w +
                qb.x * cb.x + qb.y * cb.y + qb.z * cb.z + qb.w * cb.w;
    dot += __shfl_xor(dot, 1);
    dot += __shfl_xor(dot, 2);
    dot += __shfl_xor(dot, 4);
    mx = fmaxf(mx, dot);
    sm += dot;
  }
  if (sp == 0) M[bh * LL + q] = mx - sm * (1.0f / SK);
}

// ---------------------------------------------------------------------------
// Kernel 2: top-40 of M[b,h,:] via full bitonic sort of 2048 packed u64
// keys in LDS. key = (ordered_float<<32)|~idx -> ascending sort tail =
// top-40 by (value, lowest idx) -- same selected set as lax.top_k.
// 66 stages x (4 compare-swaps/thread) x 256 thr, one barrier per stage.
// ---------------------------------------------------------------------------
__global__ __launch_bounds__(256) void k_topk(const float* __restrict__ M,
                                              int* __restrict__ Mtop) {
  int bh = blockIdx.x;
  int t = threadIdx.x;
  __shared__ unsigned long long sk[LL];
  for (int i = t; i < LL; i += 256) {
    unsigned u = __float_as_uint(M[bh * LL + i]);
    u = (u & 0x80000000u) ? ~u : (u | 0x80000000u);   // order-preserving map
    sk[i] = ((unsigned long long)u << 32) | (unsigned)(~i);
  }
  __syncthreads();
  for (int k = 2; k <= LL; k <<= 1) {
    for (int j = k >> 1; j > 0; j >>= 1) {
#pragma unroll
      for (int m = 0; m < LL / 512; m++) {   // 1024 pairs / 256 thr
        int p = t + m * 256;
        int i = ((p & ~(j - 1)) << 1) | (p & (j - 1));
        int l = i | j;
        unsigned long long a = sk[i], c = sk[l];
        bool asc = (i & k) == 0;
        if ((a > c) == asc) { sk[i] = c; sk[l] = a; }
      }
      __syncthreads();
    }
  }
  if (t < UU) {
    int e = (int)(~(unsigned)sk[LL - 1 - t]) & (LL - 1);
    Mtop[bh * UU + t] = e;
  }
}

// ---------------------------------------------------------------------------
// Cumsum stage A: 16-row chunk sums, vectorized.
// ---------------------------------------------------------------------------
__global__ __launch_bounds__(64) void k_chunksum16(const float* __restrict__ V,
                                                   float* __restrict__ CS16) {
  int j = blockIdx.x;                 // 0..4095
  int xcd = j & 7, r = j >> 3;        // r 0..511
  int bh = (xcd << 2) | (r >> 7);
  int c = r & 127;
  int b = bh >> 3, h = bh & 7;
  int t = threadIdx.x, d4 = t & 15, r4 = t >> 4;
  const float4* vp = reinterpret_cast<const float4*>(
      V + ((size_t)((b * LL + c * 16 + r4 * 4) * HH + h)) * DD) + d4;
  float4 v0 = vp[0], v1 = vp[128], v2 = vp[256], v3 = vp[384];
  float4 s;
  s.x = v0.x + v1.x + v2.x + v3.x;
  s.y = v0.y + v1.y + v2.y + v3.y;
  s.z = v0.z + v1.z + v2.z + v3.z;
  s.w = v0.w + v1.w + v2.w + v3.w;
#pragma unroll
  for (int sh = 16; sh < 64; sh <<= 1) {
    s.x += __shfl_xor(s.x, sh);
    s.y += __shfl_xor(s.y, sh);
    s.z += __shfl_xor(s.z, sh);
    s.w += __shfl_xor(s.w, sh);
  }
  if (r4 == 0)
    *reinterpret_cast<float4*>(CS16 + ((size_t)bh * 128 + c) * 64 + d4 * 4) = s;
}

// ---------------------------------------------------------------------------
// Cumsum stage B: exclusive prefix over 128 chunk-sums per bh.
// ---------------------------------------------------------------------------
__global__ __launch_bounds__(256) void k_prefix16(const float* __restrict__ CS16,
                                                  float* __restrict__ PS16) {
  int bh = blockIdx.x;
  int t = threadIdx.x, w = t >> 6, d = t & 63;
  float cs[32];
  const float* base = CS16 + ((size_t)bh * 128 + w * 32) * 64 + d;
#pragma unroll
  for (int cc = 0; cc < 32; cc++) cs[cc] = base[cc * 64];
  float tot = 0.f;
#pragma unroll
  for (int cc = 0; cc < 32; cc++) tot += cs[cc];
  __shared__ float totw[4][64];
  totw[w][d] = tot;
  __syncthreads();
  float run = 0.f;
#pragma unroll
  for (int w2 = 0; w2 < 4; w2++)
    if (w2 < w) run += totw[w2][d];
  float* pbase = PS16 + ((size_t)bh * 128 + w * 32) * 64 + d;
#pragma unroll
  for (int cc = 0; cc < 32; cc++) { pbase[cc * 64] = run; run += cs[cc]; }
}

// ---------------------------------------------------------------------------
// Cumsum stage C: write Out rows. In-register 4-row prefix + shfl_up scan.
// ---------------------------------------------------------------------------
__global__ __launch_bounds__(64) void k_cumsum16(const float* __restrict__ V,
                                                 const float* __restrict__ PS16,
                                                 float* __restrict__ Out) {
  int j = blockIdx.x;
  int xcd = j & 7, r = j >> 3;
  int bh = (xcd << 2) | (r >> 7);
  int c = r & 127;
  int b = bh >> 3, h = bh & 7;
  int t = threadIdx.x, d4 = t & 15, r4 = t >> 4;
  size_t rowbase = ((size_t)((b * LL + c * 16 + r4 * 4) * HH + h)) * DD;
  const float4* vp = reinterpret_cast<const float4*>(V + rowbase) + d4;
  float4 v0 = vp[0], v1 = vp[128], v2 = vp[256], v3 = vp[384];
  float4 i0 = v0;
  float4 i1 = {i0.x + v1.x, i0.y + v1.y, i0.z + v1.z, i0.w + v1.w};
  float4 i2 = {i1.x + v2.x, i1.y + v2.y, i1.z + v2.z, i1.w + v2.w};
  float4 i3 = {i2.x + v3.x, i2.y + v3.y, i2.z + v3.z, i2.w + v3.w};
  float4 incl = i3;
  float4 u1;
  u1.x = __shfl_up(incl.x, 16); u1.y = __shfl_up(incl.y, 16);
  u1.z = __shfl_up(incl.z, 16); u1.w = __shfl_up(incl.w, 16);
  if (r4 >= 1) { incl.x += u1.x; incl.y += u1.y; incl.z += u1.z; incl.w += u1.w; }
  float4 u2;
  u2.x = __shfl_up(incl.x, 32); u2.y = __shfl_up(incl.y, 32);
  u2.z = __shfl_up(incl.z, 32); u2.w = __shfl_up(incl.w, 32);
  if (r4 >= 2) { incl.x += u2.x; incl.y += u2.y; incl.z += u2.z; incl.w += u2.w; }
  float4 ex = {incl.x - i3.x, incl.y - i3.y, incl.z - i3.z, incl.w - i3.w};
  float4 ps = *reinterpret_cast<const float4*>(
      PS16 + ((size_t)bh * 128 + c) * 64 + d4 * 4);
  float4 base4 = {ps.x + ex.x, ps.y + ex.y, ps.z + ex.z, ps.w + ex.w};
  float4* op = reinterpret_cast<float4*>(Out + rowbase) + d4;
  float4 o;
  o = {base4.x + i0.x, base4.y + i0.y, base4.z + i0.z, base4.w + i0.w}; op[0]   = o;
  o = {base4.x + i1.x, base4.y + i1.y, base4.z + i1.z, base4.w + i1.w}; op[128] = o;
  o = {base4.x + i2.x, base4.y + i2.y, base4.z + i2.z, base4.w + i2.w}; op[256] = o;
  o = {base4.x + i3.x, base4.y + i3.y, base4.z + i3.z, base4.w + i3.w}; op[384] = o;
}

// ---------------------------------------------------------------------------
// Kernel 4a (primary): partial attention, 32-key segments. Block = (bh,seg).
// One-shot segment softmax; P via tiny LDS row; V segment in registers.
// ---------------------------------------------------------------------------
__global__ __launch_bounds__(256) void k_attn_part32(
    const float* __restrict__ Q, const float* __restrict__ K,
    const float* __restrict__ V, const int* __restrict__ Mtop,
    float* __restrict__ Part) {
  int j = blockIdx.x;                  // 0..2047
  int xcd = j & 7, r_ = j >> 3;        // 0..255
  int bh = (xcd << 2) | (r_ & 3);
  int seg = r_ >> 2;                   // 0..63
  int b = bh >> 3, h = bh & 7;
  int s0 = seg * 32;

  int t = threadIdx.x;
  int w = t >> 6, lane = t & 63;
  int kk = lane & 15, gg = lane >> 4;

  __shared__ float Kt[32 * LDK];
  __shared__ float psh[4][32];
  __shared__ int midx[UU];

  if (t < UU) midx[t] = Mtop[bh * UU + t];

  const float4* kg = reinterpret_cast<const float4*>(
      K + ((size_t)((b * LL + s0) * HH + h)) * DD);
#pragma unroll
  for (int i = 0; i < 2; i++) {
    int f = t + i * 256;               // 0..511 float4 slots
    int r = f >> 4, col = f & 15;
    float4 kv4 = kg[(size_t)r * (HH * DD / 4) + col];
    *reinterpret_cast<float4*>(&Kt[r * LDK + col * 4]) = kv4;
  }

  const float* vgp = V + ((size_t)((b * LL + s0) * HH + h)) * DD + lane;
  float vreg[32];
#pragma unroll
  for (int k = 0; k < 32; k++) vreg[k] = vgp[(size_t)k * (HH * DD)];

  __syncthreads();

  for (int uu = 0; uu < 10; uu++) {
    int u = w + uu * 4;
    int idx = midx[u];
    if (idx < s0) continue;            // wave-uniform skip
    int kend = idx - s0;
    if (kend > 31) kend = 31;

    const float4* qv = reinterpret_cast<const float4*>(
        Q + ((size_t)((b * LL + idx) * HH + h)) * DD + gg * 16);
    float4 qr0 = qv[0], qr1 = qv[1], qr2 = qv[2], qr3 = qv[3];

    float s0v, s1v;
    {
      const float4* kr = reinterpret_cast<const float4*>(&Kt[kk * LDK + gg * 16]);
      float4 c0 = kr[0], c1 = kr[1], c2 = kr[2], c3 = kr[3];
      float dp = qr0.x * c0.x + qr0.y * c0.y + qr0.z * c0.z + qr0.w * c0.w +
                 qr1.x * c1.x + qr1.y * c1.y + qr1.z * c1.z + qr1.w * c1.w +
                 qr2.x * c2.x + qr2.y * c2.y + qr2.z * c2.z + qr2.w * c2.w +
                 qr3.x * c3.x + qr3.y * c3.y + qr3.z * c3.z + qr3.w * c3.w;
      dp += __shfl_xor(dp, 16);
      dp += __shfl_xor(dp, 32);
      s0v = (kk <= kend) ? dp * 0.125f : -1e30f;
    }
    {
      const float4* kr = reinterpret_cast<const float4*>(&Kt[(16 + kk) * LDK + gg * 16]);
      float4 c0 = kr[0], c1 = kr[1], c2 = kr[2], c3 = kr[3];
      float dp = qr0.x * c0.x + qr0.y * c0.y + qr0.z * c0.z + qr0.w * c0.w +
                 qr1.x * c1.x + qr1.y * c1.y + qr1.z * c1.z + qr1.w * c1.w +
                 qr2.x * c2.x + qr2.y * c2.y + qr2.z * c2.z + qr2.w * c2.w +
                 qr3.x * c3.x + qr3.y * c3.y + qr3.z * c3.z + qr3.w * c3.w;
      dp += __shfl_xor(dp, 16);
      dp += __shfl_xor(dp, 32);
      s1v = (16 + kk <= kend) ? dp * 0.125f : -1e30f;
    }

    float m = fmaxf(s0v, s1v);
    m = fmaxf(m, __shfl_xor(m, 1));
    m = fmaxf(m, __shfl_xor(m, 2));
    m = fmaxf(m, __shfl_xor(m, 4));
    m = fmaxf(m, __shfl_xor(m, 8));
    float p0 = (kk <= kend) ? __expf(s0v - m) : 0.f;
    float p1 = (16 + kk <= kend) ? __expf(s1v - m) : 0.f;
    float l = p0 + p1;
    l += __shfl_xor(l, 1);
    l += __shfl_xor(l, 2);
    l += __shfl_xor(l, 4);
    l += __shfl_xor(l, 8);

    if (gg == 0) { psh[w][kk] = p0; psh[w][16 + kk] = p1; }

    float acc = 0.f;
#pragma unroll
    for (int kq = 0; kq < 8; kq++) {
      float4 pp = *reinterpret_cast<const float4*>(&psh[w][kq * 4]);
      acc += pp.x * vreg[kq * 4 + 0] + pp.y * vreg[kq * 4 + 1] +
             pp.z * vreg[kq * 4 + 2] + pp.w * vreg[kq * 4 + 3];
    }

    float* pb = Part + ((size_t)(bh * UU + u) * NSEG32 + seg) * PSTRIDE;
    __half* ph = reinterpret_cast<__half*>(pb + 2);
    ph[lane] = __float2half(acc);
    if (lane == 0) { pb[0] = m; pb[1] = l; }
  }
}

// ---------------------------------------------------------------------------
// Kernel 4a (fallback): 64-key segments.
// ---------------------------------------------------------------------------
__global__ __launch_bounds__(256) void k_attn_part64(
    const float* __restrict__ Q, const float* __restrict__ K,
    const float* __restrict__ V, const int* __restrict__ Mtop,
    float* __restrict__ Part) {
  int j = blockIdx.x;                  // 0..1023
  int xcd = j & 7, r_ = j >> 3;
  int bh = (xcd << 2) | (r_ & 3);
  int seg = r_ >> 2;                   // 0..31
  int b = bh >> 3, h = bh & 7;
  int s0 = seg * 64;

  int t = threadIdx.x;
  int w = t >> 6, lane = t & 63;
  int kk = lane & 15, gg = lane >> 4;

  __shared__ float Kt[64 * LDK];
  __shared__ float Vt[64 * LDK];
  __shared__ int midx[UU];

  if (t < UU) midx[t] = Mtop[bh * UU + t];

  const float4* kg = reinterpret_cast<const float4*>(
      K + ((size_t)((b * LL + s0) * HH + h)) * DD);
  const float4* vg = reinterpret_cast<const float4*>(
      V + ((size_t)((b * LL + s0) * HH + h)) * DD);
#pragma unroll
  for (int i = 0; i < 4; i++) {
    int f = t + i * 256;
    int r = f >> 4, col = f & 15;
    float4 kv4 = kg[(size_t)r * (HH * DD / 4) + col];
    float4 vv4 = vg[(size_t)r * (HH * DD / 4) + col];
    *reinterpret_cast<float4*>(&Kt[r * LDK + col * 4]) = kv4;
    *reinterpret_cast<float4*>(&Vt[r * LDK + col * 4]) = vv4;
  }
  __syncthreads();

  for (int uu = 0; uu < 10; uu++) {
    int u = w + uu * 4;
    int idx = midx[u];
    if (idx < s0) continue;
    int kend = idx - s0;
    if (kend > 63) kend = 63;

    const float4* qv = reinterpret_cast<const float4*>(
        Q + ((size_t)((b * LL + idx) * HH + h)) * DD + gg * 16);
    float4 qr0 = qv[0], qr1 = qv[1], qr2 = qv[2], qr3 = qv[3];

    float m = -1e30f, l = 0.f, acc = 0.f;
#pragma unroll
    for (int ks = 0; ks < 4; ks++) {
      if (ks * 16 > kend) break;
      int row = ks * 16 + kk;
      float dp = 0.f;
      const float4* kr = reinterpret_cast<const float4*>(&Kt[row * LDK + gg * 16]);
      float4 c0 = kr[0], c1 = kr[1], c2 = kr[2], c3 = kr[3];
      dp += qr0.x * c0.x + qr0.y * c0.y + qr0.z * c0.z + qr0.w * c0.w;
      dp += qr1.x * c1.x + qr1.y * c1.y + qr1.z * c1.z + qr1.w * c1.w;
      dp += qr2.x * c2.x + qr2.y * c2.y + qr2.z * c2.z + qr2.w * c2.w;
      dp += qr3.x * c3.x + qr3.y * c3.y + qr3.z * c3.z + qr3.w * c3.w;
      dp += __shfl_xor(dp, 16);
      dp += __shfl_xor(dp, 32);
      bool valid = (row <= kend);
      float s = valid ? dp * 0.125f : -1e30f;
      float cm = s;
      cm = fmaxf(cm, __shfl_xor(cm, 1));
      cm = fmaxf(cm, __shfl_xor(cm, 2));
      cm = fmaxf(cm, __shfl_xor(cm, 4));
      cm = fmaxf(cm, __shfl_xor(cm, 8));
      float mn = fmaxf(m, cm);
      float f_ = __expf(m - mn);
      float p = valid ? __expf(s - mn) : 0.f;
      float ps = p;
      ps += __shfl_xor(ps, 1);
      ps += __shfl_xor(ps, 2);
      ps += __shfl_xor(ps, 4);
      ps += __shfl_xor(ps, 8);
      l = l * f_ + ps;
      m = mn;
      acc *= f_;
#pragma unroll
      for (int k2 = 0; k2 < 16; k2++) {
        float pk = __shfl(p, k2);
        acc += pk * Vt[(ks * 16 + k2) * LDK + lane];
      }
    }

    float* pb = Part + ((size_t)(bh * UU + u) * NSEG64 + seg) * PSTRIDE;
    __half* ph = reinterpret_cast<__half*>(pb + 2);
    ph[lane] = __float2half(acc);
    if (lane == 0) { pb[0] = m; pb[1] = l; }
  }
}

// ---------------------------------------------------------------------------
// Kernel 4b: merge segment partials per (bh,u).
// ---------------------------------------------------------------------------
__global__ __launch_bounds__(64) void k_attn_merge(
    const int* __restrict__ Mtop, const float* __restrict__ Part,
    float* __restrict__ Out, int shift, int nsegmax) {
  int blk = blockIdx.x;                // 0..1279
  int bh = blk / UU, u = blk % UU;
  int b = bh >> 3, h = bh & 7;
  int lane = threadIdx.x;
  int idx = Mtop[bh * UU + u];
  int nseg = (idx >> shift) + 1;

  const float* base = Part + (size_t)(bh * UU + u) * nsegmax * PSTRIDE;
  float ms = -1e30f, ls = 0.f;
  if (lane < nseg) { ms = base[lane * PSTRIDE]; ls = base[lane * PSTRIDE + 1]; }
  float M0 = ms;
#pragma unroll
  for (int s = 1; s < 64; s <<= 1) M0 = fmaxf(M0, __shfl_xor(M0, s));
  float e = (lane < nseg) ? __expf(ms - M0) : 0.f;
  float lt = ls * e;
#pragma unroll
  for (int s = 1; s < 64; s <<= 1) lt += __shfl_xor(lt, s);

  __shared__ float ew[64];
  ew[lane] = e;
  __syncthreads();

  float A = 0.f;
  for (int s = 0; s < nseg; s++) {
    const __half* ha = reinterpret_cast<const __half*>(base + s * PSTRIDE + 2);
    A += ew[s] * __half2float(ha[lane]);
  }
  Out[((size_t)((b * LL + idx) * HH + h)) * DD + lane] = A / lt;
}

// ---------------------------------------------------------------------------
// Last-resort fused attention (tiny workspace only).
// ---------------------------------------------------------------------------
__global__ __launch_bounds__(256) void k_attn_fused(
    const float* __restrict__ Q, const float* __restrict__ K,
    const float* __restrict__ V, const int* __restrict__ Mtop,
    float* __restrict__ Out) {
  int j = blockIdx.x;
  int xcd = j & 7, slot = j >> 3;
  int bh = (xcd << 2) | (slot / 40);
  int u = slot % 40;
  int b = bh >> 3, h = bh & 7;
  int idx = Mtop[bh * UU + u];

  int t = threadIdx.x;
  int w = t >> 6, lane = t & 63;
  int kk = lane & 15, gg = lane >> 4;

  __shared__ float Kt[64 * LDK];
  __shared__ float Vt[64 * LDK];
  __shared__ float qs[64];

  const float* qp = Q + ((size_t)((b * LL + idx) * HH + h)) * DD;
  if (t < 64) qs[t] = qp[t] * 0.125f;
  __syncthreads();

  float qr[16];
#pragma unroll
  for (int jj = 0; jj < 16; jj++) qr[jj] = qs[gg * 16 + jj];

  float m = -1e30f, l = 0.f, acc = 0.f;
  int nch = (idx + 64) >> 6;

  for (int ch = 0; ch < nch; ch++) {
    __syncthreads();
    const float4* kg = reinterpret_cast<const float4*>(K + ((size_t)((b * LL + ch * 64) * HH + h)) * DD);
    const float4* vg = reinterpret_cast<const float4*>(V + ((size_t)((b * LL + ch * 64) * HH + h)) * DD);
#pragma unroll
    for (int i = 0; i < 4; i++) {
      int f = t + i * 256;
      int r = f >> 4, col = f & 15;
      float4 kv4 = kg[(size_t)r * (HH * DD / 4) + col];
      float4 vv4 = vg[(size_t)r * (HH * DD / 4) + col];
      *reinterpret_cast<float4*>(&Kt[r * LDK + col * 4]) = kv4;
      *reinterpret_cast<float4*>(&Vt[r * LDK + col * 4]) = vv4;
    }
    __syncthreads();

    int row = w * 16 + kk;
    int key = ch * 64 + row;
    float dp = 0.f;
#pragma unroll
    for (int jj = 0; jj < 4; jj++) {
      float4 kv4 = *reinterpret_cast<const float4*>(&Kt[row * LDK + gg * 16 + jj * 4]);
      dp += qr[jj * 4 + 0] * kv4.x + qr[jj * 4 + 1] * kv4.y +
            qr[jj * 4 + 2] * kv4.z + qr[jj * 4 + 3] * kv4.w;
    }
    dp += __shfl_xor(dp, 16);
    dp += __shfl_xor(dp, 32);
    bool valid = (key <= idx);
    float s = valid ? dp : -1e30f;
    float cm = s;
    cm = fmaxf(cm, __shfl_xor(cm, 1));
    cm = fmaxf(cm, __shfl_xor(cm, 2));
    cm = fmaxf(cm, __shfl_xor(cm, 4));
    cm = fmaxf(cm, __shfl_xor(cm, 8));
    float mn = fmaxf(m, cm);
    float f_ = __expf(m - mn);
    float p = valid ? __expf(s - mn) : 0.f;
    float ps = p;
    ps += __shfl_xor(ps, 1);
    ps += __shfl_xor(ps, 2);
    ps += __shfl_xor(ps, 4);
    ps += __shfl_xor(ps, 8);
    l = l * f_ + ps;
    m = mn;
    acc *= f_;
#pragma unroll
    for (int k2 = 0; k2 < 16; k2++) {
      float pk = __shfl(p, k2);
      acc += pk * Vt[(w * 16 + k2) * LDK + lane];
    }
  }

  __syncthreads();
  float* mw = Kt;
  float* lw = Kt + 8;
  float* aw = Vt;
  if (lane == 0) { mw[w] = m; lw[w] = l; }
  aw[w * 64 + lane] = acc;
  __syncthreads();
  if (w == 0) {
    float M0 = fmaxf(fmaxf(mw[0], mw[1]), fmaxf(mw[2], mw[3]));
    float Lt = 0.f, A = 0.f;
#pragma unroll
    for (int i = 0; i < 4; i++) {
      float e = __expf(mw[i] - M0);
      Lt += lw[i] * e;
      A += aw[i * 64 + lane] * e;
    }
    Out[((size_t)((b * LL + idx) * HH + h)) * DD + lane] = A / Lt;
  }
}

// ---------------------------------------------------------------------------
extern "C" void kernel_launch(void* const* d_in, const int* in_sizes, int n_in,
                              void* d_out, int out_size, void* d_ws, size_t ws_size,
                              hipStream_t stream) {
  const float* Q = (const float*)d_in[0];
  const float* K = (const float*)d_in[1];
  const float* V = (const float*)d_in[2];
  const int* IS = (const int*)d_in[3];
  float* Out = (float*)d_out;

  float* M = (float*)d_ws;                          // 65536 f
  float* CS16 = M + BB * HH * LL;                   // 262144 f
  float* PS16 = CS16 + BB * HH * 128 * DD;          // 262144 f
  int* Mtop = (int*)(PS16 + BB * HH * 128 * DD);    // 1280 i
  float* Part = (float*)(Mtop + BB * HH * UU);
  size_t fixed = (size_t)(BB * HH * LL + 2 * BB * HH * 128 * DD) * 4 +
                 (size_t)(BB * HH * UU) * 4;                      // ~2.37 MB
  size_t need32 = fixed + (size_t)(BB * HH * UU) * NSEG32 * PSTRIDE * 4;  // ~13.5 MB
  size_t need64 = fixed + (size_t)(BB * HH * UU) * NSEG64 * PSTRIDE * 4;  // ~7.9 MB

  k_sample_score<<<2048, 256, 0, stream>>>(Q, K, IS, M);
  k_topk<<<BB * HH, 256, 0, stream>>>(M, Mtop);
  k_chunksum16<<<4096, 64, 0, stream>>>(V, CS16);
  k_prefix16<<<BB * HH, 256, 0, stream>>>(CS16, PS16);
  k_cumsum16<<<4096, 64, 0, stream>>>(V, PS16, Out);
  if (ws_size >= need32) {
    k_attn_part32<<<2048, 256, 0, stream>>>(Q, K, V, Mtop, Part);
    k_attn_merge<<<BB * HH * UU, 64, 0, stream>>>(Mtop, Part, Out, 5, NSEG32);
  } else if (ws_size >= need64) {
    k_attn_part64<<<1024, 256, 0, stream>>>(Q, K, V, Mtop, Part);
    k_attn_merge<<<BB * HH * UU, 64, 0, stream>>>(Mtop, Part, Out, 6, NSEG64);
  } else {
    k_attn_fused<<<BB * HH * UU, 256, 0, stream>>>(Q, K, V, Mtop, Out);
  }
}

// Round 10
// 160.003 us; speedup vs baseline: 1.7317x; 1.1334x over previous
//
#include <hip/hip_runtime.h>
#include <hip/hip_bf16.h>
#include <hip/hip_fp16.h>
#include <cstdint>

// ProbSparse attention (Informer). B=4, L=2048, H=8, D=64, sample_k=u=40.
#define BB 4
#define LL 2048
#define HH 8
#define DD 64
#define SK 40
#define UU 40
#define LDK 68     // LDS row pitch (floats): 68 ≡ 4 mod 32 banks
#define NSEG32 64  // 64 segments of 32 keys (primary path)
#define NSEG64 32  // 32 segments of 64 keys (fallback path)
#define PSTRIDE 34 // Part entry: [f32 m][f32 l][64 x half] = 136 B = 34 floats

// ---------------------------------------------------------------------------
// Kernel 1: M[b,h,q] = max_s(Q·K_s) - mean_s(Q·K_s).
// Block 256 = 32 queries x 8 lanes; lane sp reads K-row floats [sp*4..+4)
// and [32+sp*4..+4): 8 lanes x 16B = 1 contiguous 128B L2 line per instr.
// ---------------------------------------------------------------------------
__global__ __launch_bounds__(256) void k_sample_score(
    const float* __restrict__ Q, const float* __restrict__ K,
    const int* __restrict__ idxs, float* __restrict__ M) {
  int j = blockIdx.x;                 // 0..2047
  int xcd = j & 7, r = j >> 3;        // r 0..255
  int bh = (xcd << 2) | (r >> 6);     // 4 bh per XCD
  int qc = r & 63;                    // 64 q-chunks of 32
  int b = bh >> 3, h = bh & 7;
  int t = threadIdx.x;
  int ql = t >> 3, sp = t & 7;        // 32 queries x 8 sub-parts
  int q = qc * 32 + ql;

  __shared__ int sidx[SK][32];        // transposed sample indices
  for (int i = t; i < SK * 32; i += 256)
    sidx[i >> 5][i & 31] = idxs[(qc * 32 + (i & 31)) * SK + (i >> 5)];
  __syncthreads();

  const float* qrow = Q + ((size_t)((b * LL + q) * HH + h)) * DD;
  float4 qa = *reinterpret_cast<const float4*>(qrow + sp * 4);
  float4 qb = *reinterpret_cast<const float4*>(qrow + 32 + sp * 4);

  const float* kb = K + (size_t)b * (LL * HH * DD) + h * DD;
  float mx = -1e30f, sm = 0.f;
#pragma unroll 4
  for (int s = 0; s < SK; s++) {
    int ks = sidx[s][ql];
    const float* kr = kb + (size_t)ks * (HH * DD);
    float4 ca = *reinterpret_cast<const float4*>(kr + sp * 4);
    float4 cb = *reinterpret_cast<const float4*>(kr + 32 + sp * 4);
    float dot = qa.x * ca.x + qa.y * ca.y + qa.z * ca.z + qa.w * ca.w +
                qb.x * cb.x + qb.y * cb.y + qb.z * cb.z + qb.w * cb.w;
    dot += __shfl_xor(dot, 1);
    dot += __shfl_xor(dot, 2);
    dot += __shfl_xor(dot, 4);
    mx = fmaxf(mx, dot);
    sm += dot;
  }
  if (sp == 0) M[bh * LL + q] = mx - sm * (1.0f / SK);
}

// ---------------------------------------------------------------------------
// Kernel 2: top-40 SET of M[b,h,:] via 4-level radix-select on ordered-u32
// keys. Selected set == lax.top_k's (value desc, lowest-index ties); the
// downstream scatter is order-independent so the set suffices.
// Level: 256-bin LDS histogram (8 vals/thread in regs) -> wave-0 shfl
// suffix-scan -> threshold byte. Then one compaction pass.
// ---------------------------------------------------------------------------
__global__ __launch_bounds__(256) void k_topk(const float* __restrict__ M,
                                              int* __restrict__ Mtop) {
  int bh = blockIdx.x;
  int t = threadIdx.x;
  __shared__ int hist[256];
  __shared__ int eqbuf[LL];
  __shared__ int selcnt, eqcnt, T_s, gt_s;

  unsigned vals[8];
#pragma unroll
  for (int i = 0; i < 8; i++) {
    unsigned u = __float_as_uint(M[bh * LL + i * 256 + t]);
    vals[i] = (u & 0x80000000u) ? ~u : (u | 0x80000000u);  // order-preserving
  }

  unsigned prefix = 0;
  int rem = UU;
  for (int lvl = 0; lvl < 4; lvl++) {
    int sh = 24 - 8 * lvl;
    hist[t] = 0;
    if (t == 0) { T_s = 0; gt_s = 0; }
    __syncthreads();
#pragma unroll
    for (int i = 0; i < 8; i++) {
      unsigned v = vals[i];
      bool act = (((unsigned long long)v >> (sh + 8)) == (unsigned long long)prefix);
      if (act) atomicAdd(&hist[(v >> sh) & 255], 1);
    }
    __syncthreads();
    if (t < 64) {
      int h0 = hist[t * 4], h1 = hist[t * 4 + 1];
      int h2 = hist[t * 4 + 2], h3 = hist[t * 4 + 3];
      int gs = h0 + h1 + h2 + h3;
      int acc = gs;                        // inclusive suffix over lanes
#pragma unroll
      for (int off = 1; off < 64; off <<= 1) {
        int x = __shfl_down(acc, off);
        if (t + off < 64) acc += x;
      }
      int sufGT = acc - gs;                // sum over lanes > this lane
      int s3 = h3 + sufGT;
      int s2 = h2 + s3;
      int s1 = h1 + s2;
      int s0 = h0 + s1;
      if (s0 > rem && s1 <= rem)    { T_s = t * 4 + 0; gt_s = s1; }
      if (s1 > rem && s2 <= rem)    { T_s = t * 4 + 1; gt_s = s2; }
      if (s2 > rem && s3 <= rem)    { T_s = t * 4 + 2; gt_s = s3; }
      if (s3 > rem && sufGT <= rem) { T_s = t * 4 + 3; gt_s = sufGT; }
    }
    __syncthreads();
    prefix = (prefix << 8) | (unsigned)T_s;
    rem -= gt_s;
    __syncthreads();
  }
  unsigned tv = prefix;                    // exact 32-bit threshold key

  if (t == 0) { selcnt = 0; eqcnt = 0; }
  __syncthreads();
#pragma unroll
  for (int i = 0; i < 8; i++) {
    unsigned v = vals[i];
    int idx = i * 256 + t;
    if (v > tv) {
      int p = atomicAdd(&selcnt, 1);
      Mtop[bh * UU + p] = idx;
    } else if (v == tv) {
      int p = atomicAdd(&eqcnt, 1);
      eqbuf[p] = idx;
    }
  }
  __syncthreads();
  int base = selcnt;                       // #(v > tv) = 40 - rem
  int needEq = UU - base;                  // = rem
  int E = eqcnt;
  if (needEq > 0) {
    if (E == needEq) {
      for (int e = t; e < E; e += 256)
        Mtop[bh * UU + base + e] = eqbuf[e];
    } else {
      for (int e = t; e < E; e += 256) {   // rank-select smallest indices
        int my = eqbuf[e];
        int rnk = 0;
        for (int f = 0; f < E; f++) rnk += (eqbuf[f] < my);
        if (rnk < needEq) Mtop[bh * UU + base + rnk] = my;
      }
    }
  }
}

// ---------------------------------------------------------------------------
// Cumsum stage A: 16-row chunk sums, vectorized.
// ---------------------------------------------------------------------------
__global__ __launch_bounds__(64) void k_chunksum16(const float* __restrict__ V,
                                                   float* __restrict__ CS16) {
  int j = blockIdx.x;                 // 0..4095
  int xcd = j & 7, r = j >> 3;        // r 0..511
  int bh = (xcd << 2) | (r >> 7);
  int c = r & 127;
  int b = bh >> 3, h = bh & 7;
  int t = threadIdx.x, d4 = t & 15, r4 = t >> 4;
  const float4* vp = reinterpret_cast<const float4*>(
      V + ((size_t)((b * LL + c * 16 + r4 * 4) * HH + h)) * DD) + d4;
  float4 v0 = vp[0], v1 = vp[128], v2 = vp[256], v3 = vp[384];
  float4 s;
  s.x = v0.x + v1.x + v2.x + v3.x;
  s.y = v0.y + v1.y + v2.y + v3.y;
  s.z = v0.z + v1.z + v2.z + v3.z;
  s.w = v0.w + v1.w + v2.w + v3.w;
#pragma unroll
  for (int sh = 16; sh < 64; sh <<= 1) {
    s.x += __shfl_xor(s.x, sh);
    s.y += __shfl_xor(s.y, sh);
    s.z += __shfl_xor(s.z, sh);
    s.w += __shfl_xor(s.w, sh);
  }
  if (r4 == 0)
    *reinterpret_cast<float4*>(CS16 + ((size_t)bh * 128 + c) * 64 + d4 * 4) = s;
}

// ---------------------------------------------------------------------------
// Cumsum stage B: exclusive prefix over 128 chunk-sums per bh.
// ---------------------------------------------------------------------------
__global__ __launch_bounds__(256) void k_prefix16(const float* __restrict__ CS16,
                                                  float* __restrict__ PS16) {
  int bh = blockIdx.x;
  int t = threadIdx.x, w = t >> 6, d = t & 63;
  float cs[32];
  const float* base = CS16 + ((size_t)bh * 128 + w * 32) * 64 + d;
#pragma unroll
  for (int cc = 0; cc < 32; cc++) cs[cc] = base[cc * 64];
  float tot = 0.f;
#pragma unroll
  for (int cc = 0; cc < 32; cc++) tot += cs[cc];
  __shared__ float totw[4][64];
  totw[w][d] = tot;
  __syncthreads();
  float run = 0.f;
#pragma unroll
  for (int w2 = 0; w2 < 4; w2++)
    if (w2 < w) run += totw[w2][d];
  float* pbase = PS16 + ((size_t)bh * 128 + w * 32) * 64 + d;
#pragma unroll
  for (int cc = 0; cc < 32; cc++) { pbase[cc * 64] = run; run += cs[cc]; }
}

// ---------------------------------------------------------------------------
// Cumsum stage C: write Out rows. In-register 4-row prefix + shfl_up scan.
// ---------------------------------------------------------------------------
__global__ __launch_bounds__(64) void k_cumsum16(const float* __restrict__ V,
                                                 const float* __restrict__ PS16,
                                                 float* __restrict__ Out) {
  int j = blockIdx.x;
  int xcd = j & 7, r = j >> 3;
  int bh = (xcd << 2) | (r >> 7);
  int c = r & 127;
  int b = bh >> 3, h = bh & 7;
  int t = threadIdx.x, d4 = t & 15, r4 = t >> 4;
  size_t rowbase = ((size_t)((b * LL + c * 16 + r4 * 4) * HH + h)) * DD;
  const float4* vp = reinterpret_cast<const float4*>(V + rowbase) + d4;
  float4 v0 = vp[0], v1 = vp[128], v2 = vp[256], v3 = vp[384];
  float4 i0 = v0;
  float4 i1 = {i0.x + v1.x, i0.y + v1.y, i0.z + v1.z, i0.w + v1.w};
  float4 i2 = {i1.x + v2.x, i1.y + v2.y, i1.z + v2.z, i1.w + v2.w};
  float4 i3 = {i2.x + v3.x, i2.y + v3.y, i2.z + v3.z, i2.w + v3.w};
  float4 incl = i3;
  float4 u1;
  u1.x = __shfl_up(incl.x, 16); u1.y = __shfl_up(incl.y, 16);
  u1.z = __shfl_up(incl.z, 16); u1.w = __shfl_up(incl.w, 16);
  if (r4 >= 1) { incl.x += u1.x; incl.y += u1.y; incl.z += u1.z; incl.w += u1.w; }
  float4 u2;
  u2.x = __shfl_up(incl.x, 32); u2.y = __shfl_up(incl.y, 32);
  u2.z = __shfl_up(incl.z, 32); u2.w = __shfl_up(incl.w, 32);
  if (r4 >= 2) { incl.x += u2.x; incl.y += u2.y; incl.z += u2.z; incl.w += u2.w; }
  float4 ex = {incl.x - i3.x, incl.y - i3.y, incl.z - i3.z, incl.w - i3.w};
  float4 ps = *reinterpret_cast<const float4*>(
      PS16 + ((size_t)bh * 128 + c) * 64 + d4 * 4);
  float4 base4 = {ps.x + ex.x, ps.y + ex.y, ps.z + ex.z, ps.w + ex.w};
  float4* op = reinterpret_cast<float4*>(Out + rowbase) + d4;
  float4 o;
  o = {base4.x + i0.x, base4.y + i0.y, base4.z + i0.z, base4.w + i0.w}; op[0]   = o;
  o = {base4.x + i1.x, base4.y + i1.y, base4.z + i1.z, base4.w + i1.w}; op[128] = o;
  o = {base4.x + i2.x, base4.y + i2.y, base4.z + i2.z, base4.w + i2.w}; op[256] = o;
  o = {base4.x + i3.x, base4.y + i3.y, base4.z + i3.z, base4.w + i3.w}; op[384] = o;
}

// ---------------------------------------------------------------------------
// Kernel 4a (primary): partial attention, 32-key segments. Block = (bh,seg).
// One-shot segment softmax; P via tiny LDS row; V segment in registers.
// ---------------------------------------------------------------------------
__global__ __launch_bounds__(256) void k_attn_part32(
    const float* __restrict__ Q, const float* __restrict__ K,
    const float* __restrict__ V, const int* __restrict__ Mtop,
    float* __restrict__ Part) {
  int j = blockIdx.x;                  // 0..2047
  int xcd = j & 7, r_ = j >> 3;        // 0..255
  int bh = (xcd << 2) | (r_ & 3);
  int seg = r_ >> 2;                   // 0..63
  int b = bh >> 3, h = bh & 7;
  int s0 = seg * 32;

  int t = threadIdx.x;
  int w = t >> 6, lane = t & 63;
  int kk = lane & 15, gg = lane >> 4;

  __shared__ float Kt[32 * LDK];
  __shared__ float psh[4][32];
  __shared__ int midx[UU];

  if (t < UU) midx[t] = Mtop[bh * UU + t];

  const float4* kg = reinterpret_cast<const float4*>(
      K + ((size_t)((b * LL + s0) * HH + h)) * DD);
#pragma unroll
  for (int i = 0; i < 2; i++) {
    int f = t + i * 256;               // 0..511 float4 slots
    int r = f >> 4, col = f & 15;
    float4 kv4 = kg[(size_t)r * (HH * DD / 4) + col];
    *reinterpret_cast<float4*>(&Kt[r * LDK + col * 4]) = kv4;
  }

  const float* vgp = V + ((size_t)((b * LL + s0) * HH + h)) * DD + lane;
  float vreg[32];
#pragma unroll
  for (int k = 0; k < 32; k++) vreg[k] = vgp[(size_t)k * (HH * DD)];

  __syncthreads();

  for (int uu = 0; uu < 10; uu++) {
    int u = w + uu * 4;
    int idx = midx[u];
    if (idx < s0) continue;            // wave-uniform skip
    int kend = idx - s0;
    if (kend > 31) kend = 31;

    const float4* qv = reinterpret_cast<const float4*>(
        Q + ((size_t)((b * LL + idx) * HH + h)) * DD + gg * 16);
    float4 qr0 = qv[0], qr1 = qv[1], qr2 = qv[2], qr3 = qv[3];

    float s0v, s1v;
    {
      const float4* kr = reinterpret_cast<const float4*>(&Kt[kk * LDK + gg * 16]);
      float4 c0 = kr[0], c1 = kr[1], c2 = kr[2], c3 = kr[3];
      float dp = qr0.x * c0.x + qr0.y * c0.y + qr0.z * c0.z + qr0.w * c0.w +
                 qr1.x * c1.x + qr1.y * c1.y + qr1.z * c1.z + qr1.w * c1.w +
                 qr2.x * c2.x + qr2.y * c2.y + qr2.z * c2.z + qr2.w * c2.w +
                 qr3.x * c3.x + qr3.y * c3.y + qr3.z * c3.z + qr3.w * c3.w;
      dp += __shfl_xor(dp, 16);
      dp += __shfl_xor(dp, 32);
      s0v = (kk <= kend) ? dp * 0.125f : -1e30f;
    }
    {
      const float4* kr = reinterpret_cast<const float4*>(&Kt[(16 + kk) * LDK + gg * 16]);
      float4 c0 = kr[0], c1 = kr[1], c2 = kr[2], c3 = kr[3];
      float dp = qr0.x * c0.x + qr0.y * c0.y + qr0.z * c0.z + qr0.w * c0.w +
                 qr1.x * c1.x + qr1.y * c1.y + qr1.z * c1.z + qr1.w * c1.w +
                 qr2.x * c2.x + qr2.y * c2.y + qr2.z * c2.z + qr2.w * c2.w +
                 qr3.x * c3.x + qr3.y * c3.y + qr3.z * c3.z + qr3.w * c3.w;
      dp += __shfl_xor(dp, 16);
      dp += __shfl_xor(dp, 32);
      s1v = (16 + kk <= kend) ? dp * 0.125f : -1e30f;
    }

    float m = fmaxf(s0v, s1v);
    m = fmaxf(m, __shfl_xor(m, 1));
    m = fmaxf(m, __shfl_xor(m, 2));
    m = fmaxf(m, __shfl_xor(m, 4));
    m = fmaxf(m, __shfl_xor(m, 8));
    float p0 = (kk <= kend) ? __expf(s0v - m) : 0.f;
    float p1 = (16 + kk <= kend) ? __expf(s1v - m) : 0.f;
    float l = p0 + p1;
    l += __shfl_xor(l, 1);
    l += __shfl_xor(l, 2);
    l += __shfl_xor(l, 4);
    l += __shfl_xor(l, 8);

    if (gg == 0) { psh[w][kk] = p0; psh[w][16 + kk] = p1; }

    float acc = 0.f;
#pragma unroll
    for (int kq = 0; kq < 8; kq++) {
      float4 pp = *reinterpret_cast<const float4*>(&psh[w][kq * 4]);
      acc += pp.x * vreg[kq * 4 + 0] + pp.y * vreg[kq * 4 + 1] +
             pp.z * vreg[kq * 4 + 2] + pp.w * vreg[kq * 4 + 3];
    }

    float* pb = Part + ((size_t)(bh * UU + u) * NSEG32 + seg) * PSTRIDE;
    __half* ph = reinterpret_cast<__half*>(pb + 2);
    ph[lane] = __float2half(acc);
    if (lane == 0) { pb[0] = m; pb[1] = l; }
  }
}

// ---------------------------------------------------------------------------
// Kernel 4a (fallback): 64-key segments.
// ---------------------------------------------------------------------------
__global__ __launch_bounds__(256) void k_attn_part64(
    const float* __restrict__ Q, const float* __restrict__ K,
    const float* __restrict__ V, const int* __restrict__ Mtop,
    float* __restrict__ Part) {
  int j = blockIdx.x;                  // 0..1023
  int xcd = j & 7, r_ = j >> 3;
  int bh = (xcd << 2) | (r_ & 3);
  int seg = r_ >> 2;                   // 0..31
  int b = bh >> 3, h = bh & 7;
  int s0 = seg * 64;

  int t = threadIdx.x;
  int w = t >> 6, lane = t & 63;
  int kk = lane & 15, gg = lane >> 4;

  __shared__ float Kt[64 * LDK];
  __shared__ float Vt[64 * LDK];
  __shared__ int midx[UU];

  if (t < UU) midx[t] = Mtop[bh * UU + t];

  const float4* kg = reinterpret_cast<const float4*>(
      K + ((size_t)((b * LL + s0) * HH + h)) * DD);
  const float4* vg = reinterpret_cast<const float4*>(
      V + ((size_t)((b * LL + s0) * HH + h)) * DD);
#pragma unroll
  for (int i = 0; i < 4; i++) {
    int f = t + i * 256;
    int r = f >> 4, col = f & 15;
    float4 kv4 = kg[(size_t)r * (HH * DD / 4) + col];
    float4 vv4 = vg[(size_t)r * (HH * DD / 4) + col];
    *reinterpret_cast<float4*>(&Kt[r * LDK + col * 4]) = kv4;
    *reinterpret_cast<float4*>(&Vt[r * LDK + col * 4]) = vv4;
  }
  __syncthreads();

  for (int uu = 0; uu < 10; uu++) {
    int u = w + uu * 4;
    int idx = midx[u];
    if (idx < s0) continue;
    int kend = idx - s0;
    if (kend > 63) kend = 63;

    const float4* qv = reinterpret_cast<const float4*>(
        Q + ((size_t)((b * LL + idx) * HH + h)) * DD + gg * 16);
    float4 qr0 = qv[0], qr1 = qv[1], qr2 = qv[2], qr3 = qv[3];

    float m = -1e30f, l = 0.f, acc = 0.f;
#pragma unroll
    for (int ks = 0; ks < 4; ks++) {
      if (ks * 16 > kend) break;
      int row = ks * 16 + kk;
      float dp = 0.f;
      const float4* kr = reinterpret_cast<const float4*>(&Kt[row * LDK + gg * 16]);
      float4 c0 = kr[0], c1 = kr[1], c2 = kr[2], c3 = kr[3];
      dp += qr0.x * c0.x + qr0.y * c0.y + qr0.z * c0.z + qr0.w * c0.w;
      dp += qr1.x * c1.x + qr1.y * c1.y + qr1.z * c1.z + qr1.w * c1.w;
      dp += qr2.x * c2.x + qr2.y * c2.y + qr2.z * c2.z + qr2.w * c2.w;
      dp += qr3.x * c3.x + qr3.y * c3.y + qr3.z * c3.z + qr3.w * c3.w;
      dp += __shfl_xor(dp, 16);
      dp += __shfl_xor(dp, 32);
      bool valid = (row <= kend);
      float s = valid ? dp * 0.125f : -1e30f;
      float cm = s;
      cm = fmaxf(cm, __shfl_xor(cm, 1));
      cm = fmaxf(cm, __shfl_xor(cm, 2));
      cm = fmaxf(cm, __shfl_xor(cm, 4));
      cm = fmaxf(cm, __shfl_xor(cm, 8));
      float mn = fmaxf(m, cm);
      float f_ = __expf(m - mn);
      float p = valid ? __expf(s - mn) : 0.f;
      float ps = p;
      ps += __shfl_xor(ps, 1);
      ps += __shfl_xor(ps, 2);
      ps += __shfl_xor(ps, 4);
      ps += __shfl_xor(ps, 8);
      l = l * f_ + ps;
      m = mn;
      acc *= f_;
#pragma unroll
      for (int k2 = 0; k2 < 16; k2++) {
        float pk = __shfl(p, k2);
        acc += pk * Vt[(ks * 16 + k2) * LDK + lane];
      }
    }

    float* pb = Part + ((size_t)(bh * UU + u) * NSEG64 + seg) * PSTRIDE;
    __half* ph = reinterpret_cast<__half*>(pb + 2);
    ph[lane] = __float2half(acc);
    if (lane == 0) { pb[0] = m; pb[1] = l; }
  }
}

// ---------------------------------------------------------------------------
// Kernel 4b: merge segment partials per (bh,u).
// ---------------------------------------------------------------------------
__global__ __launch_bounds__(64) void k_attn_merge(
    const int* __restrict__ Mtop, const float* __restrict__ Part,
    float* __restrict__ Out, int shift, int nsegmax) {
  int blk = blockIdx.x;                // 0..1279
  int bh = blk / UU, u = blk % UU;
  int b = bh >> 3, h = bh & 7;
  int lane = threadIdx.x;
  int idx = Mtop[bh * UU + u];
  int nseg = (idx >> shift) + 1;

  const float* base = Part + (size_t)(bh * UU + u) * nsegmax * PSTRIDE;
  float ms = -1e30f, ls = 0.f;
  if (lane < nseg) { ms = base[lane * PSTRIDE]; ls = base[lane * PSTRIDE + 1]; }
  float M0 = ms;
#pragma unroll
  for (int s = 1; s < 64; s <<= 1) M0 = fmaxf(M0, __shfl_xor(M0, s));
  float e = (lane < nseg) ? __expf(ms - M0) : 0.f;
  float lt = ls * e;
#pragma unroll
  for (int s = 1; s < 64; s <<= 1) lt += __shfl_xor(lt, s);

  __shared__ float ew[64];
  ew[lane] = e;
  __syncthreads();

  float A = 0.f;
  for (int s = 0; s < nseg; s++) {
    const __half* ha = reinterpret_cast<const __half*>(base + s * PSTRIDE + 2);
    A += ew[s] * __half2float(ha[lane]);
  }
  Out[((size_t)((b * LL + idx) * HH + h)) * DD + lane] = A / lt;
}

// ---------------------------------------------------------------------------
// Last-resort fused attention (tiny workspace only).
// ---------------------------------------------------------------------------
__global__ __launch_bounds__(256) void k_attn_fused(
    const float* __restrict__ Q, const float* __restrict__ K,
    const float* __restrict__ V, const int* __restrict__ Mtop,
    float* __restrict__ Out) {
  int j = blockIdx.x;
  int xcd = j & 7, slot = j >> 3;
  int bh = (xcd << 2) | (slot / 40);
  int u = slot % 40;
  int b = bh >> 3, h = bh & 7;
  int idx = Mtop[bh * UU + u];

  int t = threadIdx.x;
  int w = t >> 6, lane = t & 63;
  int kk = lane & 15, gg = lane >> 4;

  __shared__ float Kt[64 * LDK];
  __shared__ float Vt[64 * LDK];
  __shared__ float qs[64];

  const float* qp = Q + ((size_t)((b * LL + idx) * HH + h)) * DD;
  if (t < 64) qs[t] = qp[t] * 0.125f;
  __syncthreads();

  float qr[16];
#pragma unroll
  for (int jj = 0; jj < 16; jj++) qr[jj] = qs[gg * 16 + jj];

  float m = -1e30f, l = 0.f, acc = 0.f;
  int nch = (idx + 64) >> 6;

  for (int ch = 0; ch < nch; ch++) {
    __syncthreads();
    const float4* kg = reinterpret_cast<const float4*>(K + ((size_t)((b * LL + ch * 64) * HH + h)) * DD);
    const float4* vg = reinterpret_cast<const float4*>(V + ((size_t)((b * LL + ch * 64) * HH + h)) * DD);
#pragma unroll
    for (int i = 0; i < 4; i++) {
      int f = t + i * 256;
      int r = f >> 4, col = f & 15;
      float4 kv4 = kg[(size_t)r * (HH * DD / 4) + col];
      float4 vv4 = vg[(size_t)r * (HH * DD / 4) + col];
      *reinterpret_cast<float4*>(&Kt[r * LDK + col * 4]) = kv4;
      *reinterpret_cast<float4*>(&Vt[r * LDK + col * 4]) = vv4;
    }
    __syncthreads();

    int row = w * 16 + kk;
    int key = ch * 64 + row;
    float dp = 0.f;
#pragma unroll
    for (int jj = 0; jj < 4; jj++) {
      float4 kv4 = *reinterpret_cast<const float4*>(&Kt[row * LDK + gg * 16 + jj * 4]);
      dp += qr[jj * 4 + 0] * kv4.x + qr[jj * 4 + 1] * kv4.y +
            qr[jj * 4 + 2] * kv4.z + qr[jj * 4 + 3] * kv4.w;
    }
    dp += __shfl_xor(dp, 16);
    dp += __shfl_xor(dp, 32);
    bool valid = (key <= idx);
    float s = valid ? dp : -1e30f;
    float cm = s;
    cm = fmaxf(cm, __shfl_xor(cm, 1));
    cm = fmaxf(cm, __shfl_xor(cm, 2));
    cm = fmaxf(cm, __shfl_xor(cm, 4));
    cm = fmaxf(cm, __shfl_xor(cm, 8));
    float mn = fmaxf(m, cm);
    float f_ = __expf(m - mn);
    float p = valid ? __expf(s - mn) : 0.f;
    float ps = p;
    ps += __shfl_xor(ps, 1);
    ps += __shfl_xor(ps, 2);
    ps += __shfl_xor(ps, 4);
    ps += __shfl_xor(ps, 8);
    l = l * f_ + ps;
    m = mn;
    acc *= f_;
#pragma unroll
    for (int k2 = 0; k2 < 16; k2++) {
      float pk = __shfl(p, k2);
      acc += pk * Vt[(w * 16 + k2) * LDK + lane];
    }
  }

  __syncthreads();
  float* mw = Kt;
  float* lw = Kt + 8;
  float* aw = Vt;
  if (lane == 0) { mw[w] = m; lw[w] = l; }
  aw[w * 64 + lane] = acc;
  __syncthreads();
  if (w == 0) {
    float M0 = fmaxf(fmaxf(mw[0], mw[1]), fmaxf(mw[2], mw[3]));
    float Lt = 0.f, A = 0.f;
#pragma unroll
    for (int i = 0; i < 4; i++) {
      float e = __expf(mw[i] - M0);
      Lt += lw[i] * e;
      A += aw[i * 64 + lane] * e;
    }
    Out[((size_t)((b * LL + idx) * HH + h)) * DD + lane] = A / Lt;
  }
}

// ---------------------------------------------------------------------------
extern "C" void kernel_launch(void* const* d_in, const int* in_sizes, int n_in,
                              void* d_out, int out_size, void* d_ws, size_t ws_size,
                              hipStream_t stream) {
  const float* Q = (const float*)d_in[0];
  const float* K = (const float*)d_in[1];
  const float* V = (const float*)d_in[2];
  const int* IS = (const int*)d_in[3];
  float* Out = (float*)d_out;

  float* M = (float*)d_ws;                          // 65536 f
  float* CS16 = M + BB * HH * LL;                   // 262144 f
  float* PS16 = CS16 + BB * HH * 128 * DD;          // 262144 f
  int* Mtop = (int*)(PS16 + BB * HH * 128 * DD);    // 1280 i
  float* Part = (float*)(Mtop + BB * HH * UU);
  size_t fixed = (size_t)(BB * HH * LL + 2 * BB * HH * 128 * DD) * 4 +
                 (size_t)(BB * HH * UU) * 4;                      // ~2.37 MB
  size_t need32 = fixed + (size_t)(BB * HH * UU) * NSEG32 * PSTRIDE * 4;  // ~13.5 MB
  size_t need64 = fixed + (size_t)(BB * HH * UU) * NSEG64 * PSTRIDE * 4;  // ~7.9 MB

  k_sample_score<<<2048, 256, 0, stream>>>(Q, K, IS, M);
  k_topk<<<BB * HH, 256, 0, stream>>>(M, Mtop);
  k_chunksum16<<<4096, 64, 0, stream>>>(V, CS16);
  k_prefix16<<<BB * HH, 256, 0, stream>>>(CS16, PS16);
  k_cumsum16<<<4096, 64, 0, stream>>>(V, PS16, Out);
  if (ws_size >= need32) {
    k_attn_part32<<<2048, 256, 0, stream>>>(Q, K, V, Mtop, Part);
    k_attn_merge<<<BB * HH * UU, 64, 0, stream>>>(Mtop, Part, Out, 5, NSEG32);
  } else if (ws_size >= need64) {
    k_attn_part64<<<1024, 256, 0, stream>>>(Q, K, V, Mtop, Part);
    k_attn_merge<<<BB * HH * UU, 64, 0, stream>>>(Mtop, Part, Out, 6, NSEG64);
  } else {
    k_attn_fused<<<BB * HH * UU, 256, 0, stream>>>(Q, K, V, Mtop, Out);
  }
}